// Round 1
// baseline (430.880 us; speedup 1.0000x reference)
//
#include <hip/hip_runtime.h>
#include <hip/hip_bf16.h>

using bf16 = __hip_bfloat16;
typedef __attribute__((ext_vector_type(8))) __bf16 bf16x8;
typedef __attribute__((ext_vector_type(4))) float f32x4;

namespace {

constexpr int D     = 256;
constexpr int TWOD  = 512;
constexpr int NTOK  = 32768;   // B*L
constexpr int NSLOT = 8192;    // B*N
constexpr int GG    = 64;
constexpr int KK    = 16;
constexpr int NN    = 1024;

__device__ __forceinline__ float gelu_f(float x){
  return 0.5f * x * (1.0f + erff(x * 0.70710678118654752f));
}

__device__ __forceinline__ void async_ld16(const void* g, void* l){
  typedef const __attribute__((address_space(1))) unsigned int gu32;
  typedef __attribute__((address_space(3))) unsigned int lu32;
  __builtin_amdgcn_global_load_lds((gu32*)g, (lu32*)l, 16, 0, 0);
}

struct alignas(8) bf16x4s { bf16 v[4]; };

__global__ void cvt_f32_to_bf16_k(const float4* __restrict__ in, bf16x4s* __restrict__ out, int n4){
  const int stride = gridDim.x * blockDim.x;
  for (int i = blockIdx.x*blockDim.x + threadIdx.x; i < n4; i += stride){
    float4 x = in[i];
    bf16x4s o;
    o.v[0] = __float2bfloat16(x.x);
    o.v[1] = __float2bfloat16(x.y);
    o.v[2] = __float2bfloat16(x.z);
    o.v[3] = __float2bfloat16(x.w);
    out[i] = o;
  }
}

// W (Kd x Nd row-major, f32) -> Wt (Nd x Kd row-major, bf16)
__global__ void transpose_w_k(const float* __restrict__ W, bf16* __restrict__ Wt, int Kd, int Nd){
  const int idx = blockIdx.x*256 + threadIdx.x;
  if (idx >= Kd*Nd) return;
  const int k = idx / Nd, n = idx - k*Nd;
  Wt[n*Kd + k] = __float2bfloat16(W[idx]);
}

// C = act(A @ W + bias); A: MxK row-major bf16, Wt: NxK row-major bf16 (W transposed)
template<int M, int N, int K, int ACT, int OUTBF>
__global__ void gemm_k(const bf16* __restrict__ A, const bf16* __restrict__ Wt,
                       const float* __restrict__ bias, void* __restrict__ Cout)
{
  constexpr int BM=128, BN=128, BK=32;
  __shared__ bf16 smem[(BM+BN)*BK];
  bf16* As = smem;            // [128][32]
  bf16* Bs = smem + BM*BK;    // [128][32] (n-major)
  constexpr int nblk = N/BN;
  const int bm = (int)(blockIdx.x / nblk) * BM;
  const int bn = (int)(blockIdx.x % nblk) * BN;
  const int t    = threadIdx.x;
  const int lane = t & 63;
  const int wave = t >> 6;
  const int wm = (wave >> 1) * 64, wn = (wave & 1) * 64;

  f32x4 acc[4][4] = {};

  // staging: tile 128x32 bf16 = 8192B = 2 issues of (256 thr x 16B); LDS stays linear
  const int lin0 = t, lin1 = t + 256;
  const bf16* Ag0 = A  + (size_t)(bm + (lin0>>2)) * K + (lin0&3)*8;
  const bf16* Ag1 = A  + (size_t)(bm + (lin1>>2)) * K + (lin1&3)*8;
  const bf16* Bg0 = Wt + (size_t)(bn + (lin0>>2)) * K + (lin0&3)*8;
  const bf16* Bg1 = Wt + (size_t)(bn + (lin1>>2)) * K + (lin1&3)*8;
  bf16* Al0 = As + lin0*8;
  bf16* Al1 = As + lin1*8;
  bf16* Bl0 = Bs + lin0*8;
  bf16* Bl1 = Bs + lin1*8;

  const int fRow = lane & 15;          // fragment row (A) / col (B)
  const int kOff = (lane >> 4) * 8;    // k-group

  for (int k0 = 0; k0 < K; k0 += BK){
    async_ld16(Ag0 + k0, Al0);
    async_ld16(Ag1 + k0, Al1);
    async_ld16(Bg0 + k0, Bl0);
    async_ld16(Bg1 + k0, Bl1);
    __syncthreads();               // compiler emits vmcnt(0) drain before barrier
    bf16x8 af[4], bfv[4];
#pragma unroll
    for (int i=0;i<4;i++){
      af[i]  = *reinterpret_cast<const bf16x8*>(&As[(wm + i*16 + fRow)*BK + kOff]);
      bfv[i] = *reinterpret_cast<const bf16x8*>(&Bs[(wn + i*16 + fRow)*BK + kOff]);
    }
#pragma unroll
    for (int i=0;i<4;i++)
#pragma unroll
      for (int j=0;j<4;j++)
        acc[i][j] = __builtin_amdgcn_mfma_f32_16x16x32_bf16(af[i], bfv[j], acc[i][j], 0, 0, 0);
    __syncthreads();
  }

  // C/D layout (m89/m91 verified): row=(lane>>4)*4+reg, col=lane&15
#pragma unroll
  for (int i=0;i<4;i++){
    const int row0 = bm + wm + i*16 + (lane>>4)*4;
#pragma unroll
    for (int j=0;j<4;j++){
      const int col = bn + wn + j*16 + (lane & 15);
      const float bv = bias[col];
#pragma unroll
      for (int r=0;r<4;r++){
        float v = acc[i][j][r] + bv;
        if (ACT == 1) v = gelu_f(v);
        const size_t off = (size_t)(row0 + r) * N + col;
        if (OUTBF) ((bf16*)Cout)[off] = __float2bfloat16(v);
        else       ((float*)Cout)[off] = v;
      }
    }
  }
}

// fp32 routing (argmax must match fp32 reference) + gate. One wave per token.
__global__ void route_k(const float* __restrict__ X, const float* __restrict__ Wgroup,
                        const float* __restrict__ Wslot, const bf16* __restrict__ G1,
                        const float* __restrict__ Wg2, const float* __restrict__ bg2,
                        int* __restrict__ slot_out, float* __restrict__ gate_out)
{
  __shared__ float xs[4][D];
  const int w = threadIdx.x >> 6, lane = threadIdx.x & 63;
  const int token = blockIdx.x*4 + w;
  const float* xr = X + (size_t)token * D;
  for (int i = lane; i < D; i += 64) xs[w][i] = xr[i];
  __syncthreads();

  // group logit (lane = group id), first-index-wins argmax like jnp.argmax
  float vg = 0.f;
#pragma unroll 4
  for (int d = 0; d < D; d++) vg += xs[w][d] * Wgroup[d*GG + lane];
  int ig = lane;
  for (int off = 32; off; off >>= 1){
    float ov = __shfl_xor(vg, off);
    int   oi = __shfl_xor(ig, off);
    if (ov > vg || (ov == vg && oi < ig)){ vg = ov; ig = oi; }
  }

  // slot logit on lanes 0..15
  float vs;
  if (lane < 16){
    vs = 0.f;
#pragma unroll 4
    for (int d = 0; d < D; d++) vs += xs[w][d] * Wslot[d*KK + lane];
  } else vs = -3.4e38f;
  int is = lane & 15;
  for (int off = 8; off; off >>= 1){
    float ov = __shfl_xor(vs, off);
    int   oi = __shfl_xor(is, off);
    if (ov > vs || (ov == vs && oi < is)){ vs = ov; is = oi; }
  }

  // gate = sigmoid(G1 . Wg2 + bg2)
  const bf16* g1 = G1 + (size_t)token * D;
  float vgate = 0.f;
  for (int i = lane; i < D; i += 64) vgate += __bfloat162float(g1[i]) * Wg2[i];
  for (int off = 32; off; off >>= 1) vgate += __shfl_xor(vgate, off);

  if (lane == 0){
    slot_out[token] = ig * KK + is;
    gate_out[token] = 1.f / (1.f + expf(-(vgate + bg2[0])));
  }
}

__global__ void scatter_k(const bf16* __restrict__ MSG, const float* __restrict__ gate,
                          const int* __restrict__ slot, float* __restrict__ inc)
{
  const int d  = threadIdx.x;
  const int t0 = blockIdx.x * 16;
  for (int i = 0; i < 16; i++){
    const int tok = t0 + i;
    const float g = gate[tok];
    const int s = slot[tok];
    const int b = tok >> 12;   // tok / L, L=4096
    const float v = __bfloat162float(MSG[(size_t)tok*D + d]) * g;
    atomicAdd(&inc[((size_t)(b*NN + s))*D + d], v);
  }
}

__global__ void concat_k(const float* __restrict__ S, const float* __restrict__ inc,
                         bf16* __restrict__ Hb)
{
  const int idx = blockIdx.x*256 + threadIdx.x;   // over NSLOT*TWOD
  const int r = idx >> 9, c = idx & 511;
  const float v = (c < D) ? S[(size_t)r*D + c] : inc[(size_t)r*D + (c - D)];
  Hb[idx] = __float2bfloat16(v);
}

__global__ void ln_k(const float* __restrict__ S, const float* __restrict__ Upd,
                     const float* __restrict__ lnw, const float* __restrict__ lnb,
                     float* __restrict__ out)
{
  const int r = blockIdx.x, d = threadIdx.x;
  const float v = S[(size_t)r*D + d] + Upd[(size_t)r*D + d];
  float s = v, ss = v*v;
  for (int off = 32; off; off >>= 1){ s += __shfl_xor(s, off); ss += __shfl_xor(ss, off); }
  __shared__ float ps[4], pss[4];
  const int w = d >> 6, lane = d & 63;
  if (lane == 0){ ps[w] = s; pss[w] = ss; }
  __syncthreads();
  s  = ps[0]  + ps[1]  + ps[2]  + ps[3];
  ss = pss[0] + pss[1] + pss[2] + pss[3];
  const float mu  = s * (1.f/256.f);
  const float var = ss * (1.f/256.f) - mu*mu;
  const float rs  = rsqrtf(var + 1e-5f);
  out[(size_t)r*D + d] = (v - mu) * rs * lnw[d] + lnb[d];
}

} // namespace

extern "C" void kernel_launch(void* const* d_in, const int* in_sizes, int n_in,
                              void* d_out, int out_size, void* d_ws, size_t ws_size,
                              hipStream_t stream)
{
  (void)in_sizes; (void)n_in; (void)out_size; (void)ws_size;
  const float* X   = (const float*)d_in[0];
  const float* S   = (const float*)d_in[1];
  const float* Wgr = (const float*)d_in[2];
  const float* Wsl = (const float*)d_in[3];
  const float* Wm1 = (const float*)d_in[4];
  const float* bm1 = (const float*)d_in[5];
  const float* Wm2 = (const float*)d_in[6];
  const float* bm2 = (const float*)d_in[7];
  const float* Wg1 = (const float*)d_in[8];
  const float* bg1 = (const float*)d_in[9];
  const float* Wg2 = (const float*)d_in[10];
  const float* bg2 = (const float*)d_in[11];
  const float* Wu1 = (const float*)d_in[12];
  const float* bu1 = (const float*)d_in[13];
  const float* Wu2 = (const float*)d_in[14];
  const float* bu2 = (const float*)d_in[15];
  const float* lnw = (const float*)d_in[16];
  const float* lnb = (const float*)d_in[17];
  float* out = (float*)d_out;

  char* ws = (char*)d_ws;
  // workspace layout (peak ~77.2 MB, with aliasing)
  bf16* Xb   = (bf16*)(ws + 0);            // 16,777,216 B
  bf16* H1b  = (bf16*)(ws + 16777216);     // 33,554,432 B
  bf16* MSG  = (bf16*)(ws + 50331648);     // 16,777,216 B
  bf16* Wm1t = (bf16*)(ws + 67108864);     // 512x256
  bf16* Wm2t = (bf16*)(ws + 67108864 + 262144);   // 256x512
  bf16* Wg1t = (bf16*)(ws + 67108864 + 524288);   // 256x256
  bf16* Wu1t = (bf16*)(ws + 67108864 + 655360);   // 512x512
  bf16* Wu2t = (bf16*)(ws + 67108864 + 1179648);  // 256x512
  int*   slot = (int*)  (ws + 68550656);
  float* gate = (float*)(ws + 68681728);
  float* inc  = (float*)(ws + 68812800);   // 8,388,608 B, ends 77,201,408
  bf16*  G1b  = H1b;                       // alias: H1b dead after gemm2
  bf16*  Hb   = (bf16*)(ws + 0);           // alias Xb (dead after gemm3)
  bf16*  U1b  = MSG;                       // alias MSG (dead after scatter)
  float* Upd  = (float*)(ws + 8388608);    // alias Xb second half

  cvt_f32_to_bf16_k<<<4096, 256, 0, stream>>>((const float4*)X, (bf16x4s*)Xb, NTOK*D/4);
  transpose_w_k<<<(256*512+255)/256, 256, 0, stream>>>(Wm1, Wm1t, 256, 512);
  transpose_w_k<<<(512*256+255)/256, 256, 0, stream>>>(Wm2, Wm2t, 512, 256);
  transpose_w_k<<<(256*256+255)/256, 256, 0, stream>>>(Wg1, Wg1t, 256, 256);
  transpose_w_k<<<(512*512+255)/256, 256, 0, stream>>>(Wu1, Wu1t, 512, 512);
  transpose_w_k<<<(512*256+255)/256, 256, 0, stream>>>(Wu2, Wu2t, 512, 256);

  gemm_k<NTOK, 512, 256, 1, 1><<<(NTOK/128)*(512/128), 256, 0, stream>>>(Xb,  Wm1t, bm1, H1b);
  gemm_k<NTOK, 256, 512, 0, 1><<<(NTOK/128)*(256/128), 256, 0, stream>>>(H1b, Wm2t, bm2, MSG);
  gemm_k<NTOK, 256, 256, 1, 1><<<(NTOK/128)*(256/128), 256, 0, stream>>>(Xb,  Wg1t, bg1, G1b);

  route_k<<<NTOK/4, 256, 0, stream>>>(X, Wgr, Wsl, G1b, Wg2, bg2, slot, gate);
  hipMemsetAsync(inc, 0, (size_t)NSLOT*D*sizeof(float), stream);
  scatter_k<<<NTOK/16, 256, 0, stream>>>(MSG, gate, slot, inc);
  concat_k<<<NSLOT*TWOD/256, 256, 0, stream>>>(S, inc, Hb);

  gemm_k<NSLOT, 512, 512, 1, 1><<<(NSLOT/128)*(512/128), 256, 0, stream>>>(Hb,  Wu1t, bu1, U1b);
  gemm_k<NSLOT, 256, 512, 0, 0><<<(NSLOT/128)*(256/128), 256, 0, stream>>>(U1b, Wu2t, bu2, Upd);
  ln_k<<<NSLOT, 256, 0, stream>>>(S, Upd, lnw, lnb, out);
}

// Round 2
// 362.302 us; speedup vs baseline: 1.1893x; 1.1893x over previous
//
#include <hip/hip_runtime.h>
#include <hip/hip_bf16.h>

using bf16 = __hip_bfloat16;
typedef __attribute__((ext_vector_type(8))) __bf16 bf16x8;
typedef __attribute__((ext_vector_type(4))) float f32x4;

namespace {

constexpr int D     = 256;
constexpr int TWOD  = 512;
constexpr int NTOK  = 32768;   // B*L
constexpr int NSLOT = 8192;    // B*N
constexpr int GG    = 64;
constexpr int KK    = 16;
constexpr int NN    = 1024;

__device__ __forceinline__ float gelu_f(float x){
  return 0.5f * x * (1.0f + erff(x * 0.70710678118654752f));
}

__device__ __forceinline__ float bfbits2f(unsigned short u){
  return __uint_as_float(((unsigned)u) << 16);
}

__device__ __forceinline__ void async_ld16(const void* g, void* l){
  typedef const __attribute__((address_space(1))) unsigned int gu32;
  typedef __attribute__((address_space(3))) unsigned int lu32;
  __builtin_amdgcn_global_load_lds((gu32*)g, (lu32*)l, 16, 0, 0);
}

struct alignas(8) bf16x4s { bf16 v[4]; };

__global__ void cvt_f32_to_bf16_k(const float4* __restrict__ in, bf16x4s* __restrict__ out, int n4){
  const int stride = gridDim.x * blockDim.x;
  for (int i = blockIdx.x*blockDim.x + threadIdx.x; i < n4; i += stride){
    float4 x = in[i];
    bf16x4s o;
    o.v[0] = __float2bfloat16(x.x);
    o.v[1] = __float2bfloat16(x.y);
    o.v[2] = __float2bfloat16(x.z);
    o.v[3] = __float2bfloat16(x.w);
    out[i] = o;
  }
}

// W (Kd x Nd row-major, f32) -> Wt (Nd x Kd row-major, bf16)
__global__ void transpose_w_k(const float* __restrict__ W, bf16* __restrict__ Wt, int Kd, int Nd){
  const int idx = blockIdx.x*256 + threadIdx.x;
  if (idx >= Kd*Nd) return;
  const int k = idx / Nd, n = idx - k*Nd;
  Wt[n*Kd + k] = __float2bfloat16(W[idx]);
}

// C = act(A @ W + bias); A: MxK row-major bf16, Wt: NxK row-major bf16 (W transposed)
template<int M, int N, int K, int ACT, int OUTBF>
__global__ void gemm_k(const bf16* __restrict__ A, const bf16* __restrict__ Wt,
                       const float* __restrict__ bias, void* __restrict__ Cout)
{
  constexpr int BM=128, BN=128, BK=32;
  __shared__ bf16 smem[(BM+BN)*BK];
  bf16* As = smem;            // [128][32]
  bf16* Bs = smem + BM*BK;    // [128][32] (n-major)
  constexpr int nblk = N/BN;
  const int bm = (int)(blockIdx.x / nblk) * BM;
  const int bn = (int)(blockIdx.x % nblk) * BN;
  const int t    = threadIdx.x;
  const int lane = t & 63;
  const int wave = t >> 6;
  const int wm = (wave >> 1) * 64, wn = (wave & 1) * 64;

  f32x4 acc[4][4] = {};

  // staging: tile 128x32 bf16 = 8192B = 2 issues of (256 thr x 16B); LDS stays linear
  const int lin0 = t, lin1 = t + 256;
  const bf16* Ag0 = A  + (size_t)(bm + (lin0>>2)) * K + (lin0&3)*8;
  const bf16* Ag1 = A  + (size_t)(bm + (lin1>>2)) * K + (lin1&3)*8;
  const bf16* Bg0 = Wt + (size_t)(bn + (lin0>>2)) * K + (lin0&3)*8;
  const bf16* Bg1 = Wt + (size_t)(bn + (lin1>>2)) * K + (lin1&3)*8;
  bf16* Al0 = As + lin0*8;
  bf16* Al1 = As + lin1*8;
  bf16* Bl0 = Bs + lin0*8;
  bf16* Bl1 = Bs + lin1*8;

  const int fRow = lane & 15;          // fragment row (A) / col (B)
  const int kOff = (lane >> 4) * 8;    // k-group

  for (int k0 = 0; k0 < K; k0 += BK){
    async_ld16(Ag0 + k0, Al0);
    async_ld16(Ag1 + k0, Al1);
    async_ld16(Bg0 + k0, Bl0);
    async_ld16(Bg1 + k0, Bl1);
    __syncthreads();               // compiler emits vmcnt(0) drain before barrier
    bf16x8 af[4], bfv[4];
#pragma unroll
    for (int i=0;i<4;i++){
      af[i]  = *reinterpret_cast<const bf16x8*>(&As[(wm + i*16 + fRow)*BK + kOff]);
      bfv[i] = *reinterpret_cast<const bf16x8*>(&Bs[(wn + i*16 + fRow)*BK + kOff]);
    }
#pragma unroll
    for (int i=0;i<4;i++)
#pragma unroll
      for (int j=0;j<4;j++)
        acc[i][j] = __builtin_amdgcn_mfma_f32_16x16x32_bf16(af[i], bfv[j], acc[i][j], 0, 0, 0);
    __syncthreads();
  }

  // C/D layout (m89/m91 verified): row=(lane>>4)*4+reg, col=lane&15
#pragma unroll
  for (int i=0;i<4;i++){
    const int row0 = bm + wm + i*16 + (lane>>4)*4;
#pragma unroll
    for (int j=0;j<4;j++){
      const int col = bn + wn + j*16 + (lane & 15);
      const float bv = bias[col];
#pragma unroll
      for (int r=0;r<4;r++){
        float v = acc[i][j][r] + bv;
        if (ACT == 1) v = gelu_f(v);
        const size_t off = (size_t)(row0 + r) * N + col;
        if (OUTBF) ((bf16*)Cout)[off] = __float2bfloat16(v);
        else       ((float*)Cout)[off] = v;
      }
    }
  }
}

// fp32 routing + gate, wave per token. Latency-optimized:
// 4 independent accumulators, float4 LDS broadcast of X, coalesced W column reads,
// all 64 lanes active for the 16 slot logits (4 lanes per slot, shfl combine).
__global__ void route2_k(const float* __restrict__ X, const float* __restrict__ Wgroup,
                         const float* __restrict__ Wslot, const bf16* __restrict__ G1,
                         const float* __restrict__ Wg2, const float* __restrict__ bg2,
                         int* __restrict__ slot_out, float* __restrict__ gate_out)
{
  __shared__ float4 xs4[4][64];
  const int w = threadIdx.x >> 6, lane = threadIdx.x & 63;
  const int token = blockIdx.x*4 + w;
  xs4[w][lane] = reinterpret_cast<const float4*>(X + (size_t)token * D)[lane];
  __syncthreads();

  // ---- group logits: lane = group, 64 float4 chunks, 4 accumulators ----
  float a0=0.f, a1=0.f, a2=0.f, a3=0.f;
#pragma unroll 8
  for (int c = 0; c < 64; c++){
    const float4 xv = xs4[w][c];
    const float* wp = Wgroup + (size_t)c*4*GG + lane;
    a0 = fmaf(xv.x, wp[0*GG], a0);
    a1 = fmaf(xv.y, wp[1*GG], a1);
    a2 = fmaf(xv.z, wp[2*GG], a2);
    a3 = fmaf(xv.w, wp[3*GG], a3);
  }
  float vg = (a0+a1) + (a2+a3);
  int ig = lane;
  for (int off = 32; off; off >>= 1){
    float ov = __shfl_xor(vg, off);
    int   oi = __shfl_xor(ig, off);
    if (ov > vg || (ov == vg && oi < ig)){ vg = ov; ig = oi; }
  }

  // ---- slot logits: lane = (q=lane>>4)*16 + s; each lane covers 64 dims ----
  const int s = lane & 15, q = lane >> 4;
  float b0=0.f, b1=0.f, b2=0.f, b3=0.f;
  const int c0 = q * 16;                 // float4-chunk base for this quarter
#pragma unroll 4
  for (int c = 0; c < 16; c++){
    const float4 xv = xs4[w][c0 + c];
    const float* wp = Wslot + (size_t)(c0 + c)*4*KK + s;
    b0 = fmaf(xv.x, wp[0*KK], b0);
    b1 = fmaf(xv.y, wp[1*KK], b1);
    b2 = fmaf(xv.z, wp[2*KK], b2);
    b3 = fmaf(xv.w, wp[3*KK], b3);
  }
  float vs = (b0+b1) + (b2+b3);
  vs += __shfl_xor(vs, 16);
  vs += __shfl_xor(vs, 32);              // now full dot, replicated across q
  int is = s;
  for (int off = 8; off; off >>= 1){
    float ov = __shfl_xor(vs, off);
    int   oi = __shfl_xor(is, off);
    if (ov > vs || (ov == vs && oi < is)){ vs = ov; is = oi; }
  }

  // ---- gate = sigmoid(G1 . Wg2 + bg2), 4 elems per lane ----
  const ushort4 gv = *reinterpret_cast<const ushort4*>(G1 + (size_t)token * D + lane*4);
  const float4  wg = reinterpret_cast<const float4*>(Wg2)[lane];
  float gsum = fmaf(bfbits2f(gv.x), wg.x,
               fmaf(bfbits2f(gv.y), wg.y,
               fmaf(bfbits2f(gv.z), wg.z,
                    bfbits2f(gv.w) * wg.w)));
  for (int off = 32; off; off >>= 1) gsum += __shfl_xor(gsum, off);

  if (lane == 0){
    slot_out[token] = ig * KK + is;
    gate_out[token] = 1.f / (1.f + expf(-(gsum + bg2[0])));
  }
}

__global__ void scatter_k(const bf16* __restrict__ MSG, const float* __restrict__ gate,
                          const int* __restrict__ slot, float* __restrict__ inc)
{
  const int d  = threadIdx.x;
  const int t0 = blockIdx.x * 16;
  for (int i = 0; i < 16; i++){
    const int tok = t0 + i;
    const float g = gate[tok];
    const int s = slot[tok];
    const int b = tok >> 12;   // tok / L, L=4096
    const float v = __bfloat162float(MSG[(size_t)tok*D + d]) * g;
    atomicAdd(&inc[((size_t)(b*NN + s))*D + d], v);
  }
}

__global__ void concat_k(const float* __restrict__ S, const float* __restrict__ inc,
                         bf16* __restrict__ Hb)
{
  const int idx = blockIdx.x*256 + threadIdx.x;   // over NSLOT*TWOD
  const int r = idx >> 9, c = idx & 511;
  const float v = (c < D) ? S[(size_t)r*D + c] : inc[(size_t)r*D + (c - D)];
  Hb[idx] = __float2bfloat16(v);
}

__global__ void ln_k(const float* __restrict__ S, const float* __restrict__ Upd,
                     const float* __restrict__ lnw, const float* __restrict__ lnb,
                     float* __restrict__ out)
{
  const int r = blockIdx.x, d = threadIdx.x;
  const float v = S[(size_t)r*D + d] + Upd[(size_t)r*D + d];
  float s = v, ss = v*v;
  for (int off = 32; off; off >>= 1){ s += __shfl_xor(s, off); ss += __shfl_xor(ss, off); }
  __shared__ float ps[4], pss[4];
  const int w = d >> 6, lane = d & 63;
  if (lane == 0){ ps[w] = s; pss[w] = ss; }
  __syncthreads();
  s  = ps[0]  + ps[1]  + ps[2]  + ps[3];
  ss = pss[0] + pss[1] + pss[2] + pss[3];
  const float mu  = s * (1.f/256.f);
  const float var = ss * (1.f/256.f) - mu*mu;
  const float rs  = rsqrtf(var + 1e-5f);
  out[(size_t)r*D + d] = (v - mu) * rs * lnw[d] + lnb[d];
}

} // namespace

extern "C" void kernel_launch(void* const* d_in, const int* in_sizes, int n_in,
                              void* d_out, int out_size, void* d_ws, size_t ws_size,
                              hipStream_t stream)
{
  (void)in_sizes; (void)n_in; (void)out_size; (void)ws_size;
  const float* X   = (const float*)d_in[0];
  const float* S   = (const float*)d_in[1];
  const float* Wgr = (const float*)d_in[2];
  const float* Wsl = (const float*)d_in[3];
  const float* Wm1 = (const float*)d_in[4];
  const float* bm1 = (const float*)d_in[5];
  const float* Wm2 = (const float*)d_in[6];
  const float* bm2 = (const float*)d_in[7];
  const float* Wg1 = (const float*)d_in[8];
  const float* bg1 = (const float*)d_in[9];
  const float* Wg2 = (const float*)d_in[10];
  const float* bg2 = (const float*)d_in[11];
  const float* Wu1 = (const float*)d_in[12];
  const float* bu1 = (const float*)d_in[13];
  const float* Wu2 = (const float*)d_in[14];
  const float* bu2 = (const float*)d_in[15];
  const float* lnw = (const float*)d_in[16];
  const float* lnb = (const float*)d_in[17];
  float* out = (float*)d_out;

  char* ws = (char*)d_ws;
  // workspace layout (peak ~77.2 MB, with aliasing)
  bf16* Xb   = (bf16*)(ws + 0);            // 16,777,216 B
  bf16* H1b  = (bf16*)(ws + 16777216);     // 33,554,432 B
  bf16* MSG  = (bf16*)(ws + 50331648);     // 16,777,216 B
  bf16* Wm1t = (bf16*)(ws + 67108864);     // 512x256
  bf16* Wm2t = (bf16*)(ws + 67108864 + 262144);   // 256x512
  bf16* Wg1t = (bf16*)(ws + 67108864 + 524288);   // 256x256
  bf16* Wu1t = (bf16*)(ws + 67108864 + 655360);   // 512x512
  bf16* Wu2t = (bf16*)(ws + 67108864 + 1179648);  // 256x512
  int*   slot = (int*)  (ws + 68550656);
  float* gate = (float*)(ws + 68681728);
  float* inc  = (float*)(ws + 68812800);   // 8,388,608 B, ends 77,201,408
  bf16*  G1b  = H1b;                       // alias: H1b dead after gemm2
  bf16*  Hb   = (bf16*)(ws + 0);           // alias Xb (dead after gemm3)
  bf16*  U1b  = MSG;                       // alias MSG (dead after scatter)
  float* Upd  = (float*)(ws + 8388608);    // alias Xb second half

  cvt_f32_to_bf16_k<<<4096, 256, 0, stream>>>((const float4*)X, (bf16x4s*)Xb, NTOK*D/4);
  transpose_w_k<<<(256*512+255)/256, 256, 0, stream>>>(Wm1, Wm1t, 256, 512);
  transpose_w_k<<<(512*256+255)/256, 256, 0, stream>>>(Wm2, Wm2t, 512, 256);
  transpose_w_k<<<(256*256+255)/256, 256, 0, stream>>>(Wg1, Wg1t, 256, 256);
  transpose_w_k<<<(512*512+255)/256, 256, 0, stream>>>(Wu1, Wu1t, 512, 512);
  transpose_w_k<<<(512*256+255)/256, 256, 0, stream>>>(Wu2, Wu2t, 512, 256);

  gemm_k<NTOK, 512, 256, 1, 1><<<(NTOK/128)*(512/128), 256, 0, stream>>>(Xb,  Wm1t, bm1, H1b);
  gemm_k<NTOK, 256, 512, 0, 1><<<(NTOK/128)*(256/128), 256, 0, stream>>>(H1b, Wm2t, bm2, MSG);
  gemm_k<NTOK, 256, 256, 1, 1><<<(NTOK/128)*(256/128), 256, 0, stream>>>(Xb,  Wg1t, bg1, G1b);

  route2_k<<<NTOK/4, 256, 0, stream>>>(X, Wgr, Wsl, G1b, Wg2, bg2, slot, gate);
  hipMemsetAsync(inc, 0, (size_t)NSLOT*D*sizeof(float), stream);
  scatter_k<<<NTOK/16, 256, 0, stream>>>(MSG, gate, slot, inc);
  concat_k<<<NSLOT*TWOD/256, 256, 0, stream>>>(S, inc, Hb);

  gemm_k<NSLOT, 512, 512, 1, 1><<<(NSLOT/128)*(512/128), 256, 0, stream>>>(Hb,  Wu1t, bu1, U1b);
  gemm_k<NSLOT, 256, 512, 0, 0><<<(NSLOT/128)*(256/128), 256, 0, stream>>>(U1b, Wu2t, bu2, Upd);
  ln_k<<<NSLOT, 256, 0, stream>>>(S, Upd, lnw, lnb, out);
}

// Round 3
// 329.419 us; speedup vs baseline: 1.3080x; 1.0998x over previous
//
#include <hip/hip_runtime.h>
#include <hip/hip_bf16.h>

using bf16 = __hip_bfloat16;
typedef __attribute__((ext_vector_type(8))) __bf16 bf16x8;
typedef __attribute__((ext_vector_type(4))) float f32x4;

namespace {

constexpr int D     = 256;
constexpr int TWOD  = 512;
constexpr int NTOK  = 32768;   // B*L
constexpr int NSLOT = 8192;    // B*N
constexpr int GG    = 64;
constexpr int KK    = 16;
constexpr int NN    = 1024;

__device__ __forceinline__ float gelu_f(float x){
  return 0.5f * x * (1.0f + erff(x * 0.70710678118654752f));
}

__device__ __forceinline__ float bfbits2f(unsigned short u){
  return __uint_as_float(((unsigned)u) << 16);
}

__device__ __forceinline__ void async_ld16(const void* g, void* l){
  typedef const __attribute__((address_space(1))) unsigned int gu32;
  typedef __attribute__((address_space(3))) unsigned int lu32;
  __builtin_amdgcn_global_load_lds((gu32*)g, (lu32*)l, 16, 0, 0);
}

struct alignas(8) bf16x4s { bf16 v[4]; };

__global__ void cvt_f32_to_bf16_k(const float4* __restrict__ in, bf16x4s* __restrict__ out, int n4){
  const int stride = gridDim.x * blockDim.x;
  for (int i = blockIdx.x*blockDim.x + threadIdx.x; i < n4; i += stride){
    float4 x = in[i];
    bf16x4s o;
    o.v[0] = __float2bfloat16(x.x);
    o.v[1] = __float2bfloat16(x.y);
    o.v[2] = __float2bfloat16(x.z);
    o.v[3] = __float2bfloat16(x.w);
    out[i] = o;
  }
}

// W (Kd x Nd row-major, f32) -> Wt (Nd x Kd row-major, bf16)
__global__ void transpose_w_k(const float* __restrict__ W, bf16* __restrict__ Wt, int Kd, int Nd){
  const int idx = blockIdx.x*256 + threadIdx.x;
  if (idx >= Kd*Nd) return;
  const int k = idx / Nd, n = idx - k*Nd;
  Wt[n*Kd + k] = __float2bfloat16(W[idx]);
}

// Wcat[256][80] = [Wgroup | Wslot] (fp32), row-major
__global__ void cat_w_k(const float* __restrict__ Wgr, const float* __restrict__ Wsl,
                        float* __restrict__ Wcat){
  const int idx = blockIdx.x*256 + threadIdx.x;   // over 256*80
  if (idx >= 256*80) return;
  const int k = idx / 80, c = idx - k*80;
  Wcat[idx] = (c < GG) ? Wgr[k*GG + c] : Wsl[k*KK + (c - GG)];
}

// C = act(A @ W + bias); A: MxK row-major bf16, Wt: NxK row-major bf16 (W transposed)
template<int M, int N, int K, int ACT, int OUTBF>
__global__ void gemm_k(const bf16* __restrict__ A, const bf16* __restrict__ Wt,
                       const float* __restrict__ bias, void* __restrict__ Cout)
{
  constexpr int BM=128, BN=128, BK=32;
  __shared__ bf16 smem[(BM+BN)*BK];
  bf16* As = smem;            // [128][32]
  bf16* Bs = smem + BM*BK;    // [128][32] (n-major)
  constexpr int nblk = N/BN;
  const int bm = (int)(blockIdx.x / nblk) * BM;
  const int bn = (int)(blockIdx.x % nblk) * BN;
  const int t    = threadIdx.x;
  const int lane = t & 63;
  const int wave = t >> 6;
  const int wm = (wave >> 1) * 64, wn = (wave & 1) * 64;

  f32x4 acc[4][4] = {};

  const int lin0 = t, lin1 = t + 256;
  const bf16* Ag0 = A  + (size_t)(bm + (lin0>>2)) * K + (lin0&3)*8;
  const bf16* Ag1 = A  + (size_t)(bm + (lin1>>2)) * K + (lin1&3)*8;
  const bf16* Bg0 = Wt + (size_t)(bn + (lin0>>2)) * K + (lin0&3)*8;
  const bf16* Bg1 = Wt + (size_t)(bn + (lin1>>2)) * K + (lin1&3)*8;
  bf16* Al0 = As + lin0*8;
  bf16* Al1 = As + lin1*8;
  bf16* Bl0 = Bs + lin0*8;
  bf16* Bl1 = Bs + lin1*8;

  const int fRow = lane & 15;          // fragment row (A) / col (B)
  const int kOff = (lane >> 4) * 8;    // k-group

  for (int k0 = 0; k0 < K; k0 += BK){
    async_ld16(Ag0 + k0, Al0);
    async_ld16(Ag1 + k0, Al1);
    async_ld16(Bg0 + k0, Bl0);
    async_ld16(Bg1 + k0, Bl1);
    __syncthreads();
    bf16x8 af[4], bfv[4];
#pragma unroll
    for (int i=0;i<4;i++){
      af[i]  = *reinterpret_cast<const bf16x8*>(&As[(wm + i*16 + fRow)*BK + kOff]);
      bfv[i] = *reinterpret_cast<const bf16x8*>(&Bs[(wn + i*16 + fRow)*BK + kOff]);
    }
#pragma unroll
    for (int i=0;i<4;i++)
#pragma unroll
      for (int j=0;j<4;j++)
        acc[i][j] = __builtin_amdgcn_mfma_f32_16x16x32_bf16(af[i], bfv[j], acc[i][j], 0, 0, 0);
    __syncthreads();
  }

  // C/D layout (m89/m91 verified): row=(lane>>4)*4+reg, col=lane&15
#pragma unroll
  for (int i=0;i<4;i++){
    const int row0 = bm + wm + i*16 + (lane>>4)*4;
#pragma unroll
    for (int j=0;j<4;j++){
      const int col = bn + wn + j*16 + (lane & 15);
      const float bv = bias[col];
#pragma unroll
      for (int r=0;r<4;r++){
        float v = acc[i][j][r] + bv;
        if (ACT == 1) v = gelu_f(v);
        const size_t off = (size_t)(row0 + r) * N + col;
        if (OUTBF) ((bf16*)Cout)[off] = __float2bfloat16(v);
        else       ((float*)Cout)[off] = v;
      }
    }
  }
}

// fp32 routing GEMM: C[64tok x 80col] per block, fused argmax + gate epilogue.
// W staged in LDS once per K-tile (40MB total L2 traffic vs 2GB in wave-per-token).
__global__ __launch_bounds__(256) void route3_k(
    const float* __restrict__ X, const float* __restrict__ Wcat,
    const bf16* __restrict__ G1, const float* __restrict__ Wg2,
    const float* __restrict__ bg2,
    int* __restrict__ slot_out, float* __restrict__ gate_out)
{
  __shared__ float lds[64*84 > (16*68 + 16*80) ? 64*84 : (16*68 + 16*80)]; // 21504B
  float* Xs = lds;              // [16][68]  (pad 68: stage-writes land 2 lanes/bank)
  float* Ws = lds + 16*68;      // [16][80]
  float* Cs = lds;              // [64][84]  epilogue alias

  const int t = threadIdx.x;
  const int tok0 = blockIdx.x * 64;

  // compute mapping: col c16 = t&15 (+16*cg), tokens tg*4..tg*4+3
  const int c16 = t & 15;
  const int tg  = t >> 4;
  // staging mapping: thread loads float4 X[tok0+stok][k0 + 4*skq .. +3]
  const int stok = t >> 2;
  const int skq  = t & 3;

  const float* xsrc = X + (size_t)(tok0 + stok) * D + 4*skq;

  float acc[5][4] = {};

  // preload tile 0
  float4 xr = *reinterpret_cast<const float4*>(xsrc);
  float4 wr0 = reinterpret_cast<const float4*>(Wcat)[t];
  float4 wr1;
  if (t < 64) wr1 = reinterpret_cast<const float4*>(Wcat)[256 + t];

  for (int kt = 0; kt < 16; ++kt){
    // stage regs -> LDS
    Xs[(4*skq+0)*68 + stok] = xr.x;
    Xs[(4*skq+1)*68 + stok] = xr.y;
    Xs[(4*skq+2)*68 + stok] = xr.z;
    Xs[(4*skq+3)*68 + stok] = xr.w;
    reinterpret_cast<float4*>(Ws)[t] = wr0;
    if (t < 64) reinterpret_cast<float4*>(Ws)[256 + t] = wr1;
    __syncthreads();
    if (kt < 15){
      const int k0n = (kt+1)*16;
      xr  = *reinterpret_cast<const float4*>(xsrc + k0n);
      wr0 = reinterpret_cast<const float4*>(Wcat + k0n*80)[t];
      if (t < 64) wr1 = reinterpret_cast<const float4*>(Wcat + k0n*80)[256 + t];
    }
#pragma unroll
    for (int k = 0; k < 16; ++k){
      const float4 xv = *reinterpret_cast<const float4*>(&Xs[k*68 + tg*4]);
      float wv[5];
#pragma unroll
      for (int cg = 0; cg < 5; ++cg) wv[cg] = Ws[k*80 + c16 + 16*cg];
      const float xa[4] = {xv.x, xv.y, xv.z, xv.w};
#pragma unroll
      for (int cg = 0; cg < 5; ++cg)
#pragma unroll
        for (int i = 0; i < 4; ++i)
          acc[cg][i] = fmaf(xa[i], wv[cg], acc[cg][i]);
    }
    __syncthreads();
  }

  // dump C tile to LDS
#pragma unroll
  for (int cg = 0; cg < 5; ++cg)
#pragma unroll
    for (int i = 0; i < 4; ++i)
      Cs[(tg*4 + i)*84 + c16 + 16*cg] = acc[cg][i];
  __syncthreads();

  const int w = t >> 6, lane = t & 63;
  const float4 wg = reinterpret_cast<const float4*>(Wg2)[lane];
  const float bg2v = bg2[0];
  for (int j = 0; j < 16; ++j){
    const int tok = w*16 + j;
    // group argmax (first-index-wins, fp32)
    float vg = Cs[tok*84 + lane];
    int ig = lane;
    for (int off = 32; off; off >>= 1){
      float ov = __shfl_xor(vg, off);
      int   oi = __shfl_xor(ig, off);
      if (ov > vg || (ov == vg && oi < ig)){ vg = ov; ig = oi; }
    }
    // slot argmax
    float vs = (lane < 16) ? Cs[tok*84 + 64 + lane] : -3.4e38f;
    int is = lane & 15;
    for (int off = 8; off; off >>= 1){
      float ov = __shfl_xor(vs, off);
      int   oi = __shfl_xor(is, off);
      if (ov > vs || (ov == vs && oi < is)){ vs = ov; is = oi; }
    }
    // gate = sigmoid(G1 . Wg2 + bg2)
    const ushort4 gv = *reinterpret_cast<const ushort4*>(G1 + (size_t)(tok0 + tok)*D + lane*4);
    float gs = fmaf(bfbits2f(gv.x), wg.x,
               fmaf(bfbits2f(gv.y), wg.y,
               fmaf(bfbits2f(gv.z), wg.z,
                    bfbits2f(gv.w) * wg.w)));
    for (int off = 32; off; off >>= 1) gs += __shfl_xor(gs, off);
    if (lane == 0){
      slot_out[tok0 + tok] = ig * KK + is;
      gate_out[tok0 + tok] = 1.f / (1.f + expf(-(gs + bg2v)));
    }
  }
}

__global__ void scatter_k(const bf16* __restrict__ MSG, const float* __restrict__ gate,
                          const int* __restrict__ slot, float* __restrict__ inc)
{
  const int d  = threadIdx.x;
  const int t0 = blockIdx.x * 16;
  for (int i = 0; i < 16; i++){
    const int tok = t0 + i;
    const float g = gate[tok];
    const int s = slot[tok];
    const int b = tok >> 12;   // tok / L, L=4096
    const float v = __bfloat162float(MSG[(size_t)tok*D + d]) * g;
    atomicAdd(&inc[((size_t)(b*NN + s))*D + d], v);
  }
}

__global__ void concat_k(const float* __restrict__ S, const float* __restrict__ inc,
                         bf16* __restrict__ Hb)
{
  const int idx = blockIdx.x*256 + threadIdx.x;   // over NSLOT*TWOD
  const int r = idx >> 9, c = idx & 511;
  const float v = (c < D) ? S[(size_t)r*D + c] : inc[(size_t)r*D + (c - D)];
  Hb[idx] = __float2bfloat16(v);
}

__global__ void ln_k(const float* __restrict__ S, const float* __restrict__ Upd,
                     const float* __restrict__ lnw, const float* __restrict__ lnb,
                     float* __restrict__ out)
{
  const int r = blockIdx.x, d = threadIdx.x;
  const float v = S[(size_t)r*D + d] + Upd[(size_t)r*D + d];
  float s = v, ss = v*v;
  for (int off = 32; off; off >>= 1){ s += __shfl_xor(s, off); ss += __shfl_xor(ss, off); }
  __shared__ float ps[4], pss[4];
  const int w = d >> 6, lane = d & 63;
  if (lane == 0){ ps[w] = s; pss[w] = ss; }
  __syncthreads();
  s  = ps[0]  + ps[1]  + ps[2]  + ps[3];
  ss = pss[0] + pss[1] + pss[2] + pss[3];
  const float mu  = s * (1.f/256.f);
  const float var = ss * (1.f/256.f) - mu*mu;
  const float rs  = rsqrtf(var + 1e-5f);
  out[(size_t)r*D + d] = (v - mu) * rs * lnw[d] + lnb[d];
}

} // namespace

extern "C" void kernel_launch(void* const* d_in, const int* in_sizes, int n_in,
                              void* d_out, int out_size, void* d_ws, size_t ws_size,
                              hipStream_t stream)
{
  (void)in_sizes; (void)n_in; (void)out_size; (void)ws_size;
  const float* X   = (const float*)d_in[0];
  const float* S   = (const float*)d_in[1];
  const float* Wgr = (const float*)d_in[2];
  const float* Wsl = (const float*)d_in[3];
  const float* Wm1 = (const float*)d_in[4];
  const float* bm1 = (const float*)d_in[5];
  const float* Wm2 = (const float*)d_in[6];
  const float* bm2 = (const float*)d_in[7];
  const float* Wg1 = (const float*)d_in[8];
  const float* bg1 = (const float*)d_in[9];
  const float* Wg2 = (const float*)d_in[10];
  const float* bg2 = (const float*)d_in[11];
  const float* Wu1 = (const float*)d_in[12];
  const float* bu1 = (const float*)d_in[13];
  const float* Wu2 = (const float*)d_in[14];
  const float* bu2 = (const float*)d_in[15];
  const float* lnw = (const float*)d_in[16];
  const float* lnb = (const float*)d_in[17];
  float* out = (float*)d_out;

  char* ws = (char*)d_ws;
  // workspace layout (peak ~77.2 MB, with aliasing)
  bf16* Xb   = (bf16*)(ws + 0);            // 16,777,216 B
  bf16* H1b  = (bf16*)(ws + 16777216);     // 33,554,432 B
  bf16* MSG  = (bf16*)(ws + 50331648);     // 16,777,216 B
  bf16* Wm1t = (bf16*)(ws + 67108864);     // 512x256
  bf16* Wm2t = (bf16*)(ws + 67108864 + 262144);   // 256x512
  bf16* Wg1t = (bf16*)(ws + 67108864 + 524288);   // 256x256
  bf16* Wu1t = (bf16*)(ws + 67108864 + 655360);   // 512x512
  bf16* Wu2t = (bf16*)(ws + 67108864 + 1179648);  // 256x512
  int*   slot = (int*)  (ws + 68550656);
  float* gate = (float*)(ws + 68681728);
  float* inc  = (float*)(ws + 68812800);   // 8,388,608 B, ends 77,201,408
  bf16*  G1b  = H1b;                       // alias: H1b dead after gemm2
  bf16*  Hb   = (bf16*)(ws + 0);           // alias Xb (dead after gemm3)
  bf16*  U1b  = MSG;                       // alias MSG (dead after scatter)
  float* Upd  = (float*)(ws + 8388608);    // alias Xb second half
  float* Wcat = (float*)(ws + 68812800);   // alias inc: dead before memset(inc)

  cvt_f32_to_bf16_k<<<4096, 256, 0, stream>>>((const float4*)X, (bf16x4s*)Xb, NTOK*D/4);
  transpose_w_k<<<(256*512+255)/256, 256, 0, stream>>>(Wm1, Wm1t, 256, 512);
  transpose_w_k<<<(512*256+255)/256, 256, 0, stream>>>(Wm2, Wm2t, 512, 256);
  transpose_w_k<<<(256*256+255)/256, 256, 0, stream>>>(Wg1, Wg1t, 256, 256);
  transpose_w_k<<<(512*512+255)/256, 256, 0, stream>>>(Wu1, Wu1t, 512, 512);
  transpose_w_k<<<(512*256+255)/256, 256, 0, stream>>>(Wu2, Wu2t, 512, 256);
  cat_w_k<<<(256*80+255)/256, 256, 0, stream>>>(Wgr, Wsl, Wcat);

  gemm_k<NTOK, 512, 256, 1, 1><<<(NTOK/128)*(512/128), 256, 0, stream>>>(Xb,  Wm1t, bm1, H1b);
  gemm_k<NTOK, 256, 512, 0, 1><<<(NTOK/128)*(256/128), 256, 0, stream>>>(H1b, Wm2t, bm2, MSG);
  gemm_k<NTOK, 256, 256, 1, 1><<<(NTOK/128)*(256/128), 256, 0, stream>>>(Xb,  Wg1t, bg1, G1b);

  route3_k<<<NTOK/64, 256, 0, stream>>>(X, Wcat, G1b, Wg2, bg2, slot, gate);
  hipMemsetAsync(inc, 0, (size_t)NSLOT*D*sizeof(float), stream);
  scatter_k<<<NTOK/16, 256, 0, stream>>>(MSG, gate, slot, inc);
  concat_k<<<NSLOT*TWOD/256, 256, 0, stream>>>(S, inc, Hb);

  gemm_k<NSLOT, 512, 512, 1, 1><<<(NSLOT/128)*(512/128), 256, 0, stream>>>(Hb,  Wu1t, bu1, U1b);
  gemm_k<NSLOT, 256, 512, 0, 0><<<(NSLOT/128)*(256/128), 256, 0, stream>>>(U1b, Wu2t, bu2, Upd);
  ln_k<<<NSLOT, 256, 0, stream>>>(S, Upd, lnw, lnb, out);
}

// Round 4
// 265.626 us; speedup vs baseline: 1.6221x; 1.2402x over previous
//
#include <hip/hip_runtime.h>
#include <hip/hip_bf16.h>

using bf16 = __hip_bfloat16;
typedef __attribute__((ext_vector_type(8))) __bf16 bf16x8;
typedef __attribute__((ext_vector_type(4))) float f32x4;

namespace {

constexpr int D     = 256;
constexpr int TWOD  = 512;
constexpr int NTOK  = 32768;   // B*L
constexpr int NSLOT = 8192;    // B*N
constexpr int GG    = 64;
constexpr int KK    = 16;
constexpr int NN    = 1024;

// Abramowitz–Stegun 7.1.26 rational erf, |err| <= 1.5e-7 (vs libm erff ~60 inst)
__device__ __forceinline__ float erf_fast(float x){
  const float ax = fabsf(x);
  const float tt = 1.0f / fmaf(0.3275911f, ax, 1.0f);
  float p = fmaf(1.061405429f, tt, -1.453152027f);
  p = fmaf(p, tt, 1.421413741f);
  p = fmaf(p, tt, -0.284496736f);
  p = fmaf(p, tt, 0.254829592f);
  p *= tt;
  const float e = __expf(-ax*ax);
  const float r = 1.0f - p*e;
  return copysignf(r, x);
}

__device__ __forceinline__ float gelu_f(float x){
  return 0.5f * x * (1.0f + erf_fast(x * 0.70710678118654752f));
}

__device__ __forceinline__ float bfbits2f(unsigned short u){
  return __uint_as_float(((unsigned)u) << 16);
}

__device__ __forceinline__ void async_ld16(const void* g, void* l){
  typedef const __attribute__((address_space(1))) unsigned int gu32;
  typedef __attribute__((address_space(3))) unsigned int lu32;
  __builtin_amdgcn_global_load_lds((gu32*)g, (lu32*)l, 16, 0, 0);
}

struct alignas(8) bf16x4s { bf16 v[4]; };
struct alignas(16) ushort8s { unsigned short v[8]; };

__global__ void cvt_f32_to_bf16_k(const float4* __restrict__ in, bf16x4s* __restrict__ out, int n4){
  const int stride = gridDim.x * blockDim.x;
  for (int i = blockIdx.x*blockDim.x + threadIdx.x; i < n4; i += stride){
    float4 x = in[i];
    bf16x4s o;
    o.v[0] = __float2bfloat16(x.x);
    o.v[1] = __float2bfloat16(x.y);
    o.v[2] = __float2bfloat16(x.z);
    o.v[3] = __float2bfloat16(x.w);
    out[i] = o;
  }
}

// W (Kd x Nd row-major, f32) -> Wt (Nd x Kd row-major, bf16)
__global__ void transpose_w_k(const float* __restrict__ W, bf16* __restrict__ Wt, int Kd, int Nd){
  const int idx = blockIdx.x*256 + threadIdx.x;
  if (idx >= Kd*Nd) return;
  const int k = idx / Nd, n = idx - k*Nd;
  Wt[n*Kd + k] = __float2bfloat16(W[idx]);
}

// Wcat[256][80] = [Wgroup | Wslot] (fp32), row-major
__global__ void cat_w_k(const float* __restrict__ Wgr, const float* __restrict__ Wsl,
                        float* __restrict__ Wcat){
  const int idx = blockIdx.x*256 + threadIdx.x;   // over 256*80
  if (idx >= 256*80) return;
  const int k = idx / 80, c = idx - k*80;
  Wcat[idx] = (c < GG) ? Wgr[k*GG + c] : Wsl[k*KK + (c - GG)];
}

// C = act(A @ W + bias); A: MxK row-major bf16, Wt: NxK row-major bf16.
// 2-phase double-buffered K-loop (T3 minimal recipe): stage(next) -> ds_read(cur)
// -> MFMA -> vmcnt(0)+barrier. HBM latency hides under the compute phase.
template<int M, int N, int K, int BM, int BN, int ACT, int OUTBF>
__global__ __launch_bounds__(256) void gemm_k(const bf16* __restrict__ A, const bf16* __restrict__ Wt,
                                              const float* __restrict__ bias, void* __restrict__ Cout)
{
  constexpr int BK = 32;
  constexpr int NSTEP = K / BK;
  constexpr int TILEB = (BM + BN) * BK;      // bf16 elems per buffer
  constexpr int MI = BM / 32, NI = BN / 32;  // per-wave fragment counts (2x2 waves)
  __shared__ bf16 smem[2 * TILEB];

  constexpr int nblk = N / BN;
  const int bm = (int)(blockIdx.x / nblk) * BM;
  const int bn = (int)(blockIdx.x % nblk) * BN;
  const int t = threadIdx.x, lane = t & 63, wave = t >> 6;
  const int wm = (wave >> 1) * (BM / 2), wn = (wave & 1) * (BN / 2);
  const int fRow = lane & 15, kOff = (lane >> 4) * 8;

  f32x4 acc[MI][NI] = {};

  auto stage = [&](int buf, int k0){
    bf16* As = smem + buf * TILEB;
    bf16* Bs = As + BM * BK;
#pragma unroll
    for (int i = t; i < BM * 4; i += 256)   // 16B units; row=i>>2, chunk=i&3
      async_ld16(A + (size_t)(bm + (i >> 2)) * K + k0 + (i & 3) * 8, As + i * 8);
#pragma unroll
    for (int i = t; i < BN * 4; i += 256)
      async_ld16(Wt + (size_t)(bn + (i >> 2)) * K + k0 + (i & 3) * 8, Bs + i * 8);
  };

  stage(0, 0);
  asm volatile("s_waitcnt vmcnt(0)" ::: "memory");
  __builtin_amdgcn_s_barrier();

  int cur = 0;
  for (int kt = 0; kt < NSTEP; ++kt){
    if (kt + 1 < NSTEP) stage(cur ^ 1, (kt + 1) * BK);   // prefetch next tile
    const bf16* As = smem + cur * TILEB;
    const bf16* Bs = As + BM * BK;
    bf16x8 af[MI], bfv[NI];
#pragma unroll
    for (int i = 0; i < MI; i++)
      af[i]  = *reinterpret_cast<const bf16x8*>(&As[(wm + i*16 + fRow)*BK + kOff]);
#pragma unroll
    for (int j = 0; j < NI; j++)
      bfv[j] = *reinterpret_cast<const bf16x8*>(&Bs[(wn + j*16 + fRow)*BK + kOff]);
#pragma unroll
    for (int i = 0; i < MI; i++)
#pragma unroll
      for (int j = 0; j < NI; j++)
        acc[i][j] = __builtin_amdgcn_mfma_f32_16x16x32_bf16(af[i], bfv[j], acc[i][j], 0, 0, 0);
    asm volatile("s_waitcnt vmcnt(0)" ::: "memory");    // prefetch landed (hidden under compute)
    __builtin_amdgcn_s_barrier();
    cur ^= 1;
  }

  // C/D layout (m89/m91 verified): row=(lane>>4)*4+reg, col=lane&15
#pragma unroll
  for (int i = 0; i < MI; i++){
    const int row0 = bm + wm + i*16 + (lane >> 4) * 4;
#pragma unroll
    for (int j = 0; j < NI; j++){
      const int col = bn + wn + j*16 + (lane & 15);
      const float bv = bias[col];
#pragma unroll
      for (int r = 0; r < 4; r++){
        float v = acc[i][j][r] + bv;
        if (ACT == 1) v = gelu_f(v);
        const size_t off = (size_t)(row0 + r) * N + col;
        if (OUTBF) ((bf16*)Cout)[off] = __float2bfloat16(v);
        else       ((float*)Cout)[off] = v;
      }
    }
  }
}

// fp32 routing GEMM: C[64tok x 80col] per block, fused argmax + gate epilogue.
__global__ __launch_bounds__(256) void route3_k(
    const float* __restrict__ X, const float* __restrict__ Wcat,
    const bf16* __restrict__ G1, const float* __restrict__ Wg2,
    const float* __restrict__ bg2,
    int* __restrict__ slot_out, float* __restrict__ gate_out)
{
  __shared__ float lds[64*84 > (16*68 + 16*80) ? 64*84 : (16*68 + 16*80)]; // 21504B
  float* Xs = lds;              // [16][68]
  float* Ws = lds + 16*68;      // [16][80]
  float* Cs = lds;              // [64][84]  epilogue alias

  const int t = threadIdx.x;
  const int tok0 = blockIdx.x * 64;

  const int c16 = t & 15;
  const int tg  = t >> 4;
  const int stok = t >> 2;
  const int skq  = t & 3;

  const float* xsrc = X + (size_t)(tok0 + stok) * D + 4*skq;

  float acc[5][4] = {};

  float4 xr = *reinterpret_cast<const float4*>(xsrc);
  float4 wr0 = reinterpret_cast<const float4*>(Wcat)[t];
  float4 wr1;
  if (t < 64) wr1 = reinterpret_cast<const float4*>(Wcat)[256 + t];

  for (int kt = 0; kt < 16; ++kt){
    Xs[(4*skq+0)*68 + stok] = xr.x;
    Xs[(4*skq+1)*68 + stok] = xr.y;
    Xs[(4*skq+2)*68 + stok] = xr.z;
    Xs[(4*skq+3)*68 + stok] = xr.w;
    reinterpret_cast<float4*>(Ws)[t] = wr0;
    if (t < 64) reinterpret_cast<float4*>(Ws)[256 + t] = wr1;
    __syncthreads();
    if (kt < 15){
      const int k0n = (kt+1)*16;
      xr  = *reinterpret_cast<const float4*>(xsrc + k0n);
      wr0 = reinterpret_cast<const float4*>(Wcat + k0n*80)[t];
      if (t < 64) wr1 = reinterpret_cast<const float4*>(Wcat + k0n*80)[256 + t];
    }
#pragma unroll
    for (int k = 0; k < 16; ++k){
      const float4 xv = *reinterpret_cast<const float4*>(&Xs[k*68 + tg*4]);
      float wv[5];
#pragma unroll
      for (int cg = 0; cg < 5; ++cg) wv[cg] = Ws[k*80 + c16 + 16*cg];
      const float xa[4] = {xv.x, xv.y, xv.z, xv.w};
#pragma unroll
      for (int cg = 0; cg < 5; ++cg)
#pragma unroll
        for (int i = 0; i < 4; ++i)
          acc[cg][i] = fmaf(xa[i], wv[cg], acc[cg][i]);
    }
    __syncthreads();
  }

#pragma unroll
  for (int cg = 0; cg < 5; ++cg)
#pragma unroll
    for (int i = 0; i < 4; ++i)
      Cs[(tg*4 + i)*84 + c16 + 16*cg] = acc[cg][i];
  __syncthreads();

  const int w = t >> 6, lane = t & 63;
  const float4 wg = reinterpret_cast<const float4*>(Wg2)[lane];
  const float bg2v = bg2[0];
  for (int j = 0; j < 16; ++j){
    const int tok = w*16 + j;
    float vg = Cs[tok*84 + lane];
    int ig = lane;
    for (int off = 32; off; off >>= 1){
      float ov = __shfl_xor(vg, off);
      int   oi = __shfl_xor(ig, off);
      if (ov > vg || (ov == vg && oi < ig)){ vg = ov; ig = oi; }
    }
    float vs = (lane < 16) ? Cs[tok*84 + 64 + lane] : -3.4e38f;
    int is = lane & 15;
    for (int off = 8; off; off >>= 1){
      float ov = __shfl_xor(vs, off);
      int   oi = __shfl_xor(is, off);
      if (ov > vs || (ov == vs && oi < is)){ vs = ov; is = oi; }
    }
    const ushort4 gv = *reinterpret_cast<const ushort4*>(G1 + (size_t)(tok0 + tok)*D + lane*4);
    float gs = fmaf(bfbits2f(gv.x), wg.x,
               fmaf(bfbits2f(gv.y), wg.y,
               fmaf(bfbits2f(gv.z), wg.z,
                    bfbits2f(gv.w) * wg.w)));
    for (int off = 32; off; off >>= 1) gs += __shfl_xor(gs, off);
    if (lane == 0){
      slot_out[tok0 + tok] = ig * KK + is;
      gate_out[tok0 + tok] = 1.f / (1.f + expf(-(gs + bg2v)));
    }
  }
}

__global__ void scatter_k(const bf16* __restrict__ MSG, const float* __restrict__ gate,
                          const int* __restrict__ slot, float* __restrict__ inc)
{
  const int d  = threadIdx.x;
  const int t0 = blockIdx.x * 16;
  for (int i = 0; i < 16; i++){
    const int tok = t0 + i;
    const float g = gate[tok];
    const int s = slot[tok];
    const int b = tok >> 12;   // tok / L, L=4096
    const float v = __bfloat162float(MSG[(size_t)tok*D + d]) * g;
    atomicAdd(&inc[((size_t)(b*NN + s))*D + d], v);
  }
}

__global__ void concat_k(const float* __restrict__ S, const float* __restrict__ inc,
                         bf16* __restrict__ Hb)
{
  const int i8 = blockIdx.x*256 + threadIdx.x;   // over NSLOT*TWOD/8
  const int r = i8 >> 6, c = (i8 & 63) * 8;
  const float* src = (c < D) ? (S + (size_t)r*D + c) : (inc + (size_t)r*D + (c - D));
  const float4 a = reinterpret_cast<const float4*>(src)[0];
  const float4 b = reinterpret_cast<const float4*>(src)[1];
  ushort8s o;
  o.v[0] = __bfloat16_as_ushort(__float2bfloat16(a.x));
  o.v[1] = __bfloat16_as_ushort(__float2bfloat16(a.y));
  o.v[2] = __bfloat16_as_ushort(__float2bfloat16(a.z));
  o.v[3] = __bfloat16_as_ushort(__float2bfloat16(a.w));
  o.v[4] = __bfloat16_as_ushort(__float2bfloat16(b.x));
  o.v[5] = __bfloat16_as_ushort(__float2bfloat16(b.y));
  o.v[6] = __bfloat16_as_ushort(__float2bfloat16(b.z));
  o.v[7] = __bfloat16_as_ushort(__float2bfloat16(b.w));
  reinterpret_cast<ushort8s*>(Hb)[i8] = o;
}

__global__ void ln_k(const float* __restrict__ S, const float* __restrict__ Upd,
                     const float* __restrict__ lnw, const float* __restrict__ lnb,
                     float* __restrict__ out)
{
  const int r = blockIdx.x, d = threadIdx.x;
  const float v = S[(size_t)r*D + d] + Upd[(size_t)r*D + d];
  float s = v, ss = v*v;
  for (int off = 32; off; off >>= 1){ s += __shfl_xor(s, off); ss += __shfl_xor(ss, off); }
  __shared__ float ps[4], pss[4];
  const int w = d >> 6, lane = d & 63;
  if (lane == 0){ ps[w] = s; pss[w] = ss; }
  __syncthreads();
  s  = ps[0]  + ps[1]  + ps[2]  + ps[3];
  ss = pss[0] + pss[1] + pss[2] + pss[3];
  const float mu  = s * (1.f/256.f);
  const float var = ss * (1.f/256.f) - mu*mu;
  const float rs  = rsqrtf(var + 1e-5f);
  out[(size_t)r*D + d] = (v - mu) * rs * lnw[d] + lnb[d];
}

} // namespace

extern "C" void kernel_launch(void* const* d_in, const int* in_sizes, int n_in,
                              void* d_out, int out_size, void* d_ws, size_t ws_size,
                              hipStream_t stream)
{
  (void)in_sizes; (void)n_in; (void)out_size; (void)ws_size;
  const float* X   = (const float*)d_in[0];
  const float* S   = (const float*)d_in[1];
  const float* Wgr = (const float*)d_in[2];
  const float* Wsl = (const float*)d_in[3];
  const float* Wm1 = (const float*)d_in[4];
  const float* bm1 = (const float*)d_in[5];
  const float* Wm2 = (const float*)d_in[6];
  const float* bm2 = (const float*)d_in[7];
  const float* Wg1 = (const float*)d_in[8];
  const float* bg1 = (const float*)d_in[9];
  const float* Wg2 = (const float*)d_in[10];
  const float* bg2 = (const float*)d_in[11];
  const float* Wu1 = (const float*)d_in[12];
  const float* bu1 = (const float*)d_in[13];
  const float* Wu2 = (const float*)d_in[14];
  const float* bu2 = (const float*)d_in[15];
  const float* lnw = (const float*)d_in[16];
  const float* lnb = (const float*)d_in[17];
  float* out = (float*)d_out;

  char* ws = (char*)d_ws;
  // workspace layout (peak ~77.2 MB, with aliasing)
  bf16* Xb   = (bf16*)(ws + 0);            // 16,777,216 B
  bf16* H1b  = (bf16*)(ws + 16777216);     // 33,554,432 B
  bf16* MSG  = (bf16*)(ws + 50331648);     // 16,777,216 B
  bf16* Wm1t = (bf16*)(ws + 67108864);     // 512x256
  bf16* Wm2t = (bf16*)(ws + 67108864 + 262144);   // 256x512
  bf16* Wg1t = (bf16*)(ws + 67108864 + 524288);   // 256x256
  bf16* Wu1t = (bf16*)(ws + 67108864 + 655360);   // 512x512
  bf16* Wu2t = (bf16*)(ws + 67108864 + 1179648);  // 256x512
  int*   slot = (int*)  (ws + 68550656);
  float* gate = (float*)(ws + 68681728);
  float* inc  = (float*)(ws + 68812800);   // 8,388,608 B, ends 77,201,408
  bf16*  G1b  = H1b;                       // alias: H1b dead after gemm2
  bf16*  Hb   = (bf16*)(ws + 0);           // alias Xb (dead after gemm3)
  bf16*  U1b  = MSG;                       // alias MSG (dead after scatter)
  float* Upd  = (float*)(ws + 8388608);    // alias Xb second half
  float* Wcat = (float*)(ws + 68812800);   // alias inc: dead before memset(inc)

  cvt_f32_to_bf16_k<<<4096, 256, 0, stream>>>((const float4*)X, (bf16x4s*)Xb, NTOK*D/4);
  transpose_w_k<<<(256*512+255)/256, 256, 0, stream>>>(Wm1, Wm1t, 256, 512);
  transpose_w_k<<<(512*256+255)/256, 256, 0, stream>>>(Wm2, Wm2t, 512, 256);
  transpose_w_k<<<(256*256+255)/256, 256, 0, stream>>>(Wg1, Wg1t, 256, 256);
  transpose_w_k<<<(512*512+255)/256, 256, 0, stream>>>(Wu1, Wu1t, 512, 512);
  transpose_w_k<<<(512*256+255)/256, 256, 0, stream>>>(Wu2, Wu2t, 512, 256);
  cat_w_k<<<(256*80+255)/256, 256, 0, stream>>>(Wgr, Wsl, Wcat);

  gemm_k<NTOK, 512, 256, 128, 128, 1, 1><<<(NTOK/128)*(512/128), 256, 0, stream>>>(Xb,  Wm1t, bm1, H1b);
  gemm_k<NTOK, 256, 512, 128, 128, 0, 1><<<(NTOK/128)*(256/128), 256, 0, stream>>>(H1b, Wm2t, bm2, MSG);
  gemm_k<NTOK, 256, 256, 128, 128, 1, 1><<<(NTOK/128)*(256/128), 256, 0, stream>>>(Xb,  Wg1t, bg1, G1b);

  route3_k<<<NTOK/64, 256, 0, stream>>>(X, Wcat, G1b, Wg2, bg2, slot, gate);
  hipMemsetAsync(inc, 0, (size_t)NSLOT*D*sizeof(float), stream);
  scatter_k<<<NTOK/16, 256, 0, stream>>>(MSG, gate, slot, inc);
  concat_k<<<NSLOT*TWOD/8/256, 256, 0, stream>>>(S, inc, Hb);

  gemm_k<NSLOT, 512, 512, 64, 128, 1, 1><<<(NSLOT/64)*(512/128), 256, 0, stream>>>(Hb,  Wu1t, bu1, U1b);
  gemm_k<NSLOT, 256, 512, 64, 128, 0, 0><<<(NSLOT/64)*(256/128), 256, 0, stream>>>(U1b, Wu2t, bu2, Upd);
  ln_k<<<NSLOT, 256, 0, stream>>>(S, Upd, lnw, lnb, out);
}

// Round 5
// 216.561 us; speedup vs baseline: 1.9896x; 1.2266x over previous
//
#include <hip/hip_runtime.h>
#include <hip/hip_bf16.h>

using bf16 = __hip_bfloat16;
typedef __attribute__((ext_vector_type(8))) __bf16 bf16x8;
typedef __attribute__((ext_vector_type(4))) float f32x4;

namespace {

constexpr int D     = 256;
constexpr int TWOD  = 512;
constexpr int NTOK  = 32768;   // B*L
constexpr int NSLOT = 8192;    // B*N
constexpr int GG    = 64;
constexpr int KK    = 16;
constexpr int NN    = 1024;

// Abramowitz–Stegun 7.1.26 rational erf, |err| <= 1.5e-7
__device__ __forceinline__ float erf_fast(float x){
  const float ax = fabsf(x);
  const float tt = 1.0f / fmaf(0.3275911f, ax, 1.0f);
  float p = fmaf(1.061405429f, tt, -1.453152027f);
  p = fmaf(p, tt, 1.421413741f);
  p = fmaf(p, tt, -0.284496736f);
  p = fmaf(p, tt, 0.254829592f);
  p *= tt;
  const float e = __expf(-ax*ax);
  const float r = 1.0f - p*e;
  return copysignf(r, x);
}

__device__ __forceinline__ float gelu_f(float x){
  return 0.5f * x * (1.0f + erf_fast(x * 0.70710678118654752f));
}

__device__ __forceinline__ void async_ld16(const void* g, void* l){
  typedef const __attribute__((address_space(1))) unsigned int gu32;
  typedef __attribute__((address_space(3))) unsigned int lu32;
  __builtin_amdgcn_global_load_lds((gu32*)g, (lu32*)l, 16, 0, 0);
}

struct alignas(8) bf16x4s { bf16 v[4]; };
struct alignas(16) ushort8s { unsigned short v[8]; };

__global__ void cvt_f32_to_bf16_k(const float4* __restrict__ in, bf16x4s* __restrict__ out, int n4){
  const int stride = gridDim.x * blockDim.x;
  for (int i = blockIdx.x*blockDim.x + threadIdx.x; i < n4; i += stride){
    float4 x = in[i];
    bf16x4s o;
    o.v[0] = __float2bfloat16(x.x);
    o.v[1] = __float2bfloat16(x.y);
    o.v[2] = __float2bfloat16(x.z);
    o.v[3] = __float2bfloat16(x.w);
    out[i] = o;
  }
}

// W (Kd x Nd row-major, f32) -> Wt (Nd x Kd row-major, bf16)
__global__ void transpose_w_k(const float* __restrict__ W, bf16* __restrict__ Wt, int Kd, int Nd){
  const int idx = blockIdx.x*256 + threadIdx.x;
  if (idx >= Kd*Nd) return;
  const int k = idx / Nd, n = idx - k*Nd;
  Wt[n*Kd + k] = __float2bfloat16(W[idx]);
}

// Wcat[256][80] = [Wgroup | Wslot] (fp32), row-major
__global__ void cat_w_k(const float* __restrict__ Wgr, const float* __restrict__ Wsl,
                        float* __restrict__ Wcat){
  const int idx = blockIdx.x*256 + threadIdx.x;   // over 256*80
  if (idx >= 256*80) return;
  const int k = idx / 80, c = idx - k*80;
  Wcat[idx] = (c < GG) ? Wgr[k*GG + c] : Wsl[k*KK + (c - GG)];
}

// C = act(A @ W + bias); A: MxK row-major bf16, Wt: NxK row-major bf16.
// 3-buffer 2-deep prefetch, counted vmcnt (T4), raw s_barrier (no vmcnt(0) drain
// in the main loop). Epilogue stages C through LDS for coalesced b128 stores.
template<int M, int N, int K, int BM, int BN, int ACT, int OUTBF>
__global__ __launch_bounds__(256) void gemm_k(const bf16* __restrict__ A, const bf16* __restrict__ Wt,
                                              const float* __restrict__ bias, void* __restrict__ Cout)
{
  constexpr int BK = 32;
  constexpr int NSTEP = K / BK;
  constexpr int TILEB = (BM + BN) * BK;           // bf16 elems per buffer
  constexpr int LPS   = (BM + BN) / 64;           // global_load_lds per thread per stage
  constexpr int MI = BM / 32, NI = BN / 32;
  constexpr int CTS = BN + 8;                     // LDS C-tile stride (bank spread)
  constexpr unsigned SMEM_B = (3u*TILEB*2 > (unsigned)BM*CTS*2) ? 3u*TILEB*2 : (unsigned)BM*CTS*2;
  __shared__ alignas(16) char smem[SMEM_B];
  bf16* bufs = (bf16*)smem;

  constexpr int nblk = N / BN;
  const int bm = (int)(blockIdx.x / nblk) * BM;
  const int bn = (int)(blockIdx.x % nblk) * BN;
  const int t = threadIdx.x, lane = t & 63, wave = t >> 6;
  const int wm = (wave >> 1) * (BM / 2), wn = (wave & 1) * (BN / 2);
  const int fRow = lane & 15, kOff = (lane >> 4) * 8;

  f32x4 acc[MI][NI] = {};

  auto stage = [&](int buf, int k0){
    bf16* As = bufs + buf * TILEB;
    bf16* Bs = As + BM * BK;
#pragma unroll
    for (int i = t; i < BM * 4; i += 256)
      async_ld16(A + (size_t)(bm + (i >> 2)) * K + k0 + (i & 3) * 8, As + i * 8);
#pragma unroll
    for (int i = t; i < BN * 4; i += 256)
      async_ld16(Wt + (size_t)(bn + (i >> 2)) * K + k0 + (i & 3) * 8, Bs + i * 8);
  };
  auto wait_one_stage = [&](){           // allow exactly one stage (LPS loads) in flight
    if constexpr (LPS == 4) asm volatile("s_waitcnt vmcnt(4)" ::: "memory");
    else if constexpr (LPS == 3) asm volatile("s_waitcnt vmcnt(3)" ::: "memory");
    else asm volatile("s_waitcnt vmcnt(0)" ::: "memory");
  };

  stage(0, 0);
  stage(1, BK);
  wait_one_stage();                      // buffer 0 landed (buffer 1 still in flight)

  for (int kt = 0; kt < NSTEP; ++kt){
    __builtin_amdgcn_s_barrier();        // all waves' tile-kt writes visible
    asm volatile("" ::: "memory");
    const bf16* As = bufs + (kt % 3) * TILEB;
    const bf16* Bs = As + BM * BK;
    bf16x8 af[MI], bfv[NI];
#pragma unroll
    for (int i = 0; i < MI; i++)
      af[i]  = *reinterpret_cast<const bf16x8*>(&As[(wm + i*16 + fRow)*BK + kOff]);
#pragma unroll
    for (int j = 0; j < NI; j++)
      bfv[j] = *reinterpret_cast<const bf16x8*>(&Bs[(wn + j*16 + fRow)*BK + kOff]);
    if (kt + 2 < NSTEP) stage((kt + 2) % 3, (kt + 2) * BK);   // keep 2 tiles in flight
#pragma unroll
    for (int i = 0; i < MI; i++)
#pragma unroll
      for (int j = 0; j < NI; j++)
        acc[i][j] = __builtin_amdgcn_mfma_f32_16x16x32_bf16(af[i], bfv[j], acc[i][j], 0, 0, 0);
    if (kt + 2 < NSTEP) wait_one_stage();                     // tile kt+1 ready, kt+2 in flight
    else asm volatile("s_waitcnt vmcnt(0)" ::: "memory");     // tail: drain
  }

  // epilogue
  if constexpr (OUTBF){
    __syncthreads();                    // safe to reuse smem
    bf16* Ct = (bf16*)smem;
#pragma unroll
    for (int i = 0; i < MI; i++){
      const int row0 = wm + i*16 + (lane >> 4) * 4;
#pragma unroll
      for (int j = 0; j < NI; j++){
        const int col = wn + j*16 + (lane & 15);
        const float bv = bias[bn + col];
#pragma unroll
        for (int r = 0; r < 4; r++){
          float v = acc[i][j][r] + bv;
          if (ACT) v = gelu_f(v);
          Ct[(row0 + r)*CTS + col] = __float2bfloat16(v);
        }
      }
    }
    __syncthreads();
    constexpr int U = BM * BN / 8;      // 16B units
    constexpr int CPR = BN / 8;
#pragma unroll
    for (int u = t; u < U; u += 256){
      const int row = u / CPR, c8 = (u % CPR) * 8;
      ushort8s v = *reinterpret_cast<const ushort8s*>(&Ct[row*CTS + c8]);
      *reinterpret_cast<ushort8s*>((bf16*)Cout + (size_t)(bm + row) * N + bn + c8) = v;
    }
  } else {
#pragma unroll
    for (int i = 0; i < MI; i++){
      const int row0 = bm + wm + i*16 + (lane >> 4) * 4;
#pragma unroll
      for (int j = 0; j < NI; j++){
        const int col = bn + wn + j*16 + (lane & 15);
        const float bv = bias[col];
#pragma unroll
        for (int r = 0; r < 4; r++){
          float v = acc[i][j][r] + bv;
          if (ACT) v = gelu_f(v);
          ((float*)Cout)[(size_t)(row0 + r) * N + col] = v;
        }
      }
    }
  }
}

// gelu(X@Wg1+bg1) GEMM with gate-dot epilogue: no C output; each wave reduces its
// 64-col partial of G1row . Wg2 and atomicAdds into gacc[token].
__global__ __launch_bounds__(256) void gate_gemm_k(const bf16* __restrict__ A, const bf16* __restrict__ Wt,
                                                   const float* __restrict__ bias, const float* __restrict__ Wg2,
                                                   float* __restrict__ gacc)
{
  constexpr int N = 256, K = 256, BM = 128, BN = 128, BK = 32;
  constexpr int NSTEP = K / BK, TILEB = (BM + BN) * BK;
  __shared__ alignas(16) bf16 bufs[3 * TILEB];

  constexpr int nblk = N / BN;
  const int bm = (int)(blockIdx.x / nblk) * BM;
  const int bn = (int)(blockIdx.x % nblk) * BN;
  const int t = threadIdx.x, lane = t & 63, wave = t >> 6;
  const int wm = (wave >> 1) * 64, wn = (wave & 1) * 64;
  const int fRow = lane & 15, kOff = (lane >> 4) * 8;

  f32x4 acc[4][4] = {};

  auto stage = [&](int buf, int k0){
    bf16* As = bufs + buf * TILEB;
    bf16* Bs = As + BM * BK;
#pragma unroll
    for (int i = t; i < BM * 4; i += 256)
      async_ld16(A + (size_t)(bm + (i >> 2)) * K + k0 + (i & 3) * 8, As + i * 8);
#pragma unroll
    for (int i = t; i < BN * 4; i += 256)
      async_ld16(Wt + (size_t)(bn + (i >> 2)) * K + k0 + (i & 3) * 8, Bs + i * 8);
  };

  stage(0, 0);
  stage(1, BK);
  asm volatile("s_waitcnt vmcnt(4)" ::: "memory");

  for (int kt = 0; kt < NSTEP; ++kt){
    __builtin_amdgcn_s_barrier();
    asm volatile("" ::: "memory");
    const bf16* As = bufs + (kt % 3) * TILEB;
    const bf16* Bs = As + BM * BK;
    bf16x8 af[4], bfv[4];
#pragma unroll
    for (int i = 0; i < 4; i++)
      af[i]  = *reinterpret_cast<const bf16x8*>(&As[(wm + i*16 + fRow)*BK + kOff]);
#pragma unroll
    for (int j = 0; j < 4; j++)
      bfv[j] = *reinterpret_cast<const bf16x8*>(&Bs[(wn + j*16 + fRow)*BK + kOff]);
    if (kt + 2 < NSTEP) stage((kt + 2) % 3, (kt + 2) * BK);
#pragma unroll
    for (int i = 0; i < 4; i++)
#pragma unroll
      for (int j = 0; j < 4; j++)
        acc[i][j] = __builtin_amdgcn_mfma_f32_16x16x32_bf16(af[i], bfv[j], acc[i][j], 0, 0, 0);
    if (kt + 2 < NSTEP) asm volatile("s_waitcnt vmcnt(4)" ::: "memory");
    else asm volatile("s_waitcnt vmcnt(0)" ::: "memory");
  }

  const int c16 = lane & 15, q = lane >> 4;
  float wv[4], bvv[4];
#pragma unroll
  for (int j = 0; j < 4; j++){
    const int col = bn + wn + j*16 + c16;
    wv[j] = Wg2[col];
    bvv[j] = bias[col];
  }
#pragma unroll
  for (int i = 0; i < 4; i++){
#pragma unroll
    for (int r = 0; r < 4; r++){
      float p = 0.f;
#pragma unroll
      for (int j = 0; j < 4; j++) p += gelu_f(acc[i][j][r] + bvv[j]) * wv[j];
      p += __shfl_xor(p, 1); p += __shfl_xor(p, 2); p += __shfl_xor(p, 4); p += __shfl_xor(p, 8);
      if (c16 == 0) atomicAdd(&gacc[bm + wm + i*16 + q*4 + r], p);
    }
  }
}

// fp32 routing GEMM: 128 tokens/block, per-thread tile = 8 tok x (4 contiguous
// group cols + 1 slot col). Epilogue: thread-per-token argmax (first-index-wins).
__global__ __launch_bounds__(256) void route4_k(const float* __restrict__ X,
                                                const float* __restrict__ Wcat,
                                                int* __restrict__ slot_out)
{
  __shared__ float lds[128 * 84];       // 43008 B; main loop uses first 3456 floats
  float* Xs = lds;                      // [16][136] transposed X tile
  float* Ws = lds + 16 * 136;           // [16][80]
  float* Cs = lds;                      // [128][84] epilogue alias

  const int t = threadIdx.x;
  const int tok0 = blockIdx.x * 128;
  const int cq = t & 15;                // col quad: group cols 4cq..4cq+3, slot col 64+cq
  const int tg = t >> 4;                // token group: tokens tg*8..tg*8+7
  const int stok = t >> 2, skq = t & 3; // X staging: float4 X[tok][4*skq..]

  const float* xsrc0 = X + (size_t)(tok0 + stok) * D + 4*skq;
  const float* xsrc1 = X + (size_t)(tok0 + 64 + stok) * D + 4*skq;
  const int wrow0 = t / 20,        wc0 = t - wrow0*20;        // u = t  (< 320)
  const int wrow1 = (256+t) / 20,  wc1 = (256+t) - wrow1*20;  // u = 256+t (t<64)

  float accg[8][4] = {};
  float accs[8] = {};

  float4 xr0 = *reinterpret_cast<const float4*>(xsrc0);
  float4 xr1 = *reinterpret_cast<const float4*>(xsrc1);
  float4 wr0 = *reinterpret_cast<const float4*>(Wcat + (size_t)wrow0*80 + 4*wc0);
  float4 wr1;
  if (t < 64) wr1 = *reinterpret_cast<const float4*>(Wcat + (size_t)wrow1*80 + 4*wc1);

  for (int kt = 0; kt < 16; ++kt){
    __syncthreads();                    // previous compute done
    Xs[(4*skq+0)*136 + stok] = xr0.x;
    Xs[(4*skq+1)*136 + stok] = xr0.y;
    Xs[(4*skq+2)*136 + stok] = xr0.z;
    Xs[(4*skq+3)*136 + stok] = xr0.w;
    Xs[(4*skq+0)*136 + 64 + stok] = xr1.x;
    Xs[(4*skq+1)*136 + 64 + stok] = xr1.y;
    Xs[(4*skq+2)*136 + 64 + stok] = xr1.z;
    Xs[(4*skq+3)*136 + 64 + stok] = xr1.w;
    *reinterpret_cast<float4*>(&Ws[wrow0*80 + 4*wc0]) = wr0;
    if (t < 64) *reinterpret_cast<float4*>(&Ws[wrow1*80 + 4*wc1]) = wr1;
    __syncthreads();
    if (kt < 15){
      const int ko = (kt+1)*16;
      xr0 = *reinterpret_cast<const float4*>(xsrc0 + ko);
      xr1 = *reinterpret_cast<const float4*>(xsrc1 + ko);
      wr0 = *reinterpret_cast<const float4*>(Wcat + (size_t)(ko + wrow0)*80 + 4*wc0);
      if (t < 64) wr1 = *reinterpret_cast<const float4*>(Wcat + (size_t)(ko + wrow1)*80 + 4*wc1);
    }
#pragma unroll
    for (int k = 0; k < 16; ++k){
      const float4 xa = *reinterpret_cast<const float4*>(&Xs[k*136 + tg*8]);
      const float4 xb = *reinterpret_cast<const float4*>(&Xs[k*136 + tg*8 + 4]);
      const float4 wq = *reinterpret_cast<const float4*>(&Ws[k*80 + 4*cq]);
      const float wsv = Ws[k*80 + 64 + cq];
      const float xv[8] = {xa.x, xa.y, xa.z, xa.w, xb.x, xb.y, xb.z, xb.w};
#pragma unroll
      for (int m = 0; m < 8; m++){
        accg[m][0] = fmaf(xv[m], wq.x, accg[m][0]);
        accg[m][1] = fmaf(xv[m], wq.y, accg[m][1]);
        accg[m][2] = fmaf(xv[m], wq.z, accg[m][2]);
        accg[m][3] = fmaf(xv[m], wq.w, accg[m][3]);
        accs[m]    = fmaf(xv[m], wsv,  accs[m]);
      }
    }
  }

  __syncthreads();                      // done with Xs/Ws, reuse as Cs
#pragma unroll
  for (int m = 0; m < 8; m++){
    const int tok = tg*8 + m;
    Cs[tok*84 + 4*cq + 0] = accg[m][0];
    Cs[tok*84 + 4*cq + 1] = accg[m][1];
    Cs[tok*84 + 4*cq + 2] = accg[m][2];
    Cs[tok*84 + 4*cq + 3] = accg[m][3];
    Cs[tok*84 + 64 + cq]  = accs[m];
  }
  __syncthreads();
  if (t < 128){
    const float* row = &Cs[t * 84];
    float bg = row[0]; int big = 0;
    for (int g = 1; g < 64; ++g){ const float v = row[g]; if (v > bg){ bg = v; big = g; } }
    float bs = row[64]; int bis = 0;
    for (int s2 = 1; s2 < 16; ++s2){ const float v = row[64 + s2]; if (v > bs){ bs = v; bis = s2; } }
    slot_out[tok0 + t] = big * KK + bis;
  }
}

__global__ void scatter_k(const bf16* __restrict__ MSG, const float* __restrict__ gacc,
                          const float* __restrict__ bg2, const int* __restrict__ slot,
                          float* __restrict__ inc)
{
  const int d  = threadIdx.x;
  const int t0 = blockIdx.x * 16;
  const float bg2v = bg2[0];
  for (int i = 0; i < 16; i++){
    const int tok = t0 + i;
    const float g = 1.f / (1.f + __expf(-(gacc[tok] + bg2v)));
    const int s = slot[tok];
    const int b = tok >> 12;   // tok / L, L=4096
    const float v = __bfloat162float(MSG[(size_t)tok*D + d]) * g;
    atomicAdd(&inc[((size_t)(b*NN + s))*D + d], v);
  }
}

__global__ void concat_k(const float* __restrict__ S, const float* __restrict__ inc,
                         bf16* __restrict__ Hb)
{
  const int i8 = blockIdx.x*256 + threadIdx.x;   // over NSLOT*TWOD/8
  const int r = i8 >> 6, c = (i8 & 63) * 8;
  const float* src = (c < D) ? (S + (size_t)r*D + c) : (inc + (size_t)r*D + (c - D));
  const float4 a = reinterpret_cast<const float4*>(src)[0];
  const float4 b = reinterpret_cast<const float4*>(src)[1];
  ushort8s o;
  o.v[0] = __bfloat16_as_ushort(__float2bfloat16(a.x));
  o.v[1] = __bfloat16_as_ushort(__float2bfloat16(a.y));
  o.v[2] = __bfloat16_as_ushort(__float2bfloat16(a.z));
  o.v[3] = __bfloat16_as_ushort(__float2bfloat16(a.w));
  o.v[4] = __bfloat16_as_ushort(__float2bfloat16(b.x));
  o.v[5] = __bfloat16_as_ushort(__float2bfloat16(b.y));
  o.v[6] = __bfloat16_as_ushort(__float2bfloat16(b.z));
  o.v[7] = __bfloat16_as_ushort(__float2bfloat16(b.w));
  reinterpret_cast<ushort8s*>(Hb)[i8] = o;
}

__global__ void ln_k(const float* __restrict__ S, const float* __restrict__ Upd,
                     const float* __restrict__ lnw, const float* __restrict__ lnb,
                     float* __restrict__ out)
{
  const int r = blockIdx.x, d = threadIdx.x;
  const float v = S[(size_t)r*D + d] + Upd[(size_t)r*D + d];
  float s = v, ss = v*v;
  for (int off = 32; off; off >>= 1){ s += __shfl_xor(s, off); ss += __shfl_xor(ss, off); }
  __shared__ float ps[4], pss[4];
  const int w = d >> 6, lane = d & 63;
  if (lane == 0){ ps[w] = s; pss[w] = ss; }
  __syncthreads();
  s  = ps[0]  + ps[1]  + ps[2]  + ps[3];
  ss = pss[0] + pss[1] + pss[2] + pss[3];
  const float mu  = s * (1.f/256.f);
  const float var = ss * (1.f/256.f) - mu*mu;
  const float rs  = rsqrtf(var + 1e-5f);
  out[(size_t)r*D + d] = (v - mu) * rs * lnw[d] + lnb[d];
}

} // namespace

extern "C" void kernel_launch(void* const* d_in, const int* in_sizes, int n_in,
                              void* d_out, int out_size, void* d_ws, size_t ws_size,
                              hipStream_t stream)
{
  (void)in_sizes; (void)n_in; (void)out_size; (void)ws_size;
  const float* X   = (const float*)d_in[0];
  const float* S   = (const float*)d_in[1];
  const float* Wgr = (const float*)d_in[2];
  const float* Wsl = (const float*)d_in[3];
  const float* Wm1 = (const float*)d_in[4];
  const float* bm1 = (const float*)d_in[5];
  const float* Wm2 = (const float*)d_in[6];
  const float* bm2 = (const float*)d_in[7];
  const float* Wg1 = (const float*)d_in[8];
  const float* bg1 = (const float*)d_in[9];
  const float* Wg2 = (const float*)d_in[10];
  const float* bg2 = (const float*)d_in[11];
  const float* Wu1 = (const float*)d_in[12];
  const float* bu1 = (const float*)d_in[13];
  const float* Wu2 = (const float*)d_in[14];
  const float* bu2 = (const float*)d_in[15];
  const float* lnw = (const float*)d_in[16];
  const float* lnb = (const float*)d_in[17];
  float* out = (float*)d_out;

  char* ws = (char*)d_ws;
  // workspace layout (peak ~77.2 MB, with aliasing)
  bf16* Xb   = (bf16*)(ws + 0);            // 16,777,216 B
  bf16* H1b  = (bf16*)(ws + 16777216);     // 33,554,432 B
  bf16* MSG  = (bf16*)(ws + 50331648);     // 16,777,216 B
  bf16* Wm1t = (bf16*)(ws + 67108864);     // 512x256
  bf16* Wm2t = (bf16*)(ws + 67108864 + 262144);   // 256x512
  bf16* Wg1t = (bf16*)(ws + 67108864 + 524288);   // 256x256
  bf16* Wu1t = (bf16*)(ws + 67108864 + 655360);   // 512x512
  bf16* Wu2t = (bf16*)(ws + 67108864 + 1179648);  // 256x512
  int*   slot = (int*)  (ws + 68550656);
  float* gacc = (float*)(ws + 68681728);   // 131072 B (token gate logit partials)
  float* inc  = (float*)(ws + 68812800);   // 8,388,608 B, ends 77,201,408
  bf16*  Hb   = (bf16*)(ws + 0);           // alias Xb (dead after gate_gemm)
  bf16*  U1b  = MSG;                       // alias MSG (dead after scatter)
  float* Upd  = (float*)(ws + 8388608);    // alias Xb second half
  float* Wcat = (float*)(ws + 68812800);   // alias inc: dead before memset(inc)

  cvt_f32_to_bf16_k<<<4096, 256, 0, stream>>>((const float4*)X, (bf16x4s*)Xb, NTOK*D/4);
  transpose_w_k<<<(256*512+255)/256, 256, 0, stream>>>(Wm1, Wm1t, 256, 512);
  transpose_w_k<<<(512*256+255)/256, 256, 0, stream>>>(Wm2, Wm2t, 512, 256);
  transpose_w_k<<<(256*256+255)/256, 256, 0, stream>>>(Wg1, Wg1t, 256, 256);
  transpose_w_k<<<(512*512+255)/256, 256, 0, stream>>>(Wu1, Wu1t, 512, 512);
  transpose_w_k<<<(512*256+255)/256, 256, 0, stream>>>(Wu2, Wu2t, 512, 256);
  cat_w_k<<<(256*80+255)/256, 256, 0, stream>>>(Wgr, Wsl, Wcat);

  gemm_k<NTOK, 512, 256, 128, 128, 1, 1><<<(NTOK/128)*(512/128), 256, 0, stream>>>(Xb,  Wm1t, bm1, H1b);
  gemm_k<NTOK, 256, 512, 128, 128, 0, 1><<<(NTOK/128)*(256/128), 256, 0, stream>>>(H1b, Wm2t, bm2, MSG);

  hipMemsetAsync(gacc, 0, (size_t)NTOK*sizeof(float), stream);
  gate_gemm_k<<<(NTOK/128)*2, 256, 0, stream>>>(Xb, Wg1t, bg1, Wg2, gacc);

  route4_k<<<NTOK/128, 256, 0, stream>>>(X, Wcat, slot);

  hipMemsetAsync(inc, 0, (size_t)NSLOT*D*sizeof(float), stream);
  scatter_k<<<NTOK/16, 256, 0, stream>>>(MSG, gacc, bg2, slot, inc);
  concat_k<<<NSLOT*TWOD/8/256, 256, 0, stream>>>(S, inc, Hb);

  gemm_k<NSLOT, 512, 512, 64, 128, 1, 1><<<(NSLOT/64)*(512/128), 256, 0, stream>>>(Hb,  Wu1t, bu1, U1b);
  gemm_k<NSLOT, 256, 512, 64, 128, 0, 0><<<(NSLOT/64)*(256/128), 256, 0, stream>>>(U1b, Wu2t, bu2, Upd);
  ln_k<<<NSLOT, 256, 0, stream>>>(S, Upd, lnw, lnb, out);
}

// Round 6
// 200.418 us; speedup vs baseline: 2.1499x; 1.0805x over previous
//
#include <hip/hip_runtime.h>
#include <hip/hip_bf16.h>

using bf16 = __hip_bfloat16;
typedef __attribute__((ext_vector_type(8))) __bf16 bf16x8;
typedef __attribute__((ext_vector_type(4))) float f32x4;

namespace {

constexpr int D     = 256;
constexpr int TWOD  = 512;
constexpr int NTOK  = 32768;   // B*L
constexpr int NSLOT = 8192;    // B*N
constexpr int GG    = 64;
constexpr int KK    = 16;
constexpr int NN    = 1024;

// Abramowitz–Stegun 7.1.26 rational erf, |err| <= 1.5e-7
__device__ __forceinline__ float erf_fast(float x){
  const float ax = fabsf(x);
  const float tt = 1.0f / fmaf(0.3275911f, ax, 1.0f);
  float p = fmaf(1.061405429f, tt, -1.453152027f);
  p = fmaf(p, tt, 1.421413741f);
  p = fmaf(p, tt, -0.284496736f);
  p = fmaf(p, tt, 0.254829592f);
  p *= tt;
  const float e = __expf(-ax*ax);
  const float r = 1.0f - p*e;
  return copysignf(r, x);
}

__device__ __forceinline__ float gelu_f(float x){
  return 0.5f * x * (1.0f + erf_fast(x * 0.70710678118654752f));
}

__device__ __forceinline__ float bfbits2f(unsigned short u){
  return __uint_as_float(((unsigned)u) << 16);
}

__device__ __forceinline__ void async_ld16(const void* g, void* l){
  typedef const __attribute__((address_space(1))) unsigned int gu32;
  typedef __attribute__((address_space(3))) unsigned int lu32;
  __builtin_amdgcn_global_load_lds((gu32*)g, (lu32*)l, 16, 0, 0);
}

struct alignas(8) bf16x4s { bf16 v[4]; };
struct alignas(16) ushort8s { unsigned short v[8]; };

__global__ void cvt_f32_to_bf16_k(const float4* __restrict__ in, bf16x4s* __restrict__ out, int n4){
  const int stride = gridDim.x * blockDim.x;
  for (int i = blockIdx.x*blockDim.x + threadIdx.x; i < n4; i += stride){
    float4 x = in[i];
    bf16x4s o;
    o.v[0] = __float2bfloat16(x.x);
    o.v[1] = __float2bfloat16(x.y);
    o.v[2] = __float2bfloat16(x.z);
    o.v[3] = __float2bfloat16(x.w);
    out[i] = o;
  }
}

// W (Kd x Nd row-major, f32) -> Wt (Nd x Kd row-major, bf16)
__global__ void transpose_w_k(const float* __restrict__ W, bf16* __restrict__ Wt, int Kd, int Nd){
  const int idx = blockIdx.x*256 + threadIdx.x;
  if (idx >= Kd*Nd) return;
  const int k = idx / Nd, n = idx - k*Nd;
  Wt[n*Kd + k] = __float2bfloat16(W[idx]);
}

// Wcat[256][80] = [Wgroup | Wslot] (fp32), row-major
__global__ void cat_w_k(const float* __restrict__ Wgr, const float* __restrict__ Wsl,
                        float* __restrict__ Wcat){
  const int idx = blockIdx.x*256 + threadIdx.x;   // over 256*80
  if (idx >= 256*80) return;
  const int k = idx / 80, c = idx - k*80;
  Wcat[idx] = (c < GG) ? Wgr[k*GG + c] : Wsl[k*KK + (c - GG)];
}

// ---------------------------------------------------------------------------
// Fused 2-layer MLP: C = gelu(A@W1 + b1) @ W2 + b2  (EPI=0: bf16 store;
// EPI=1: fused residual+LayerNorm vs S, f32 store).
// A: MxK bf16; W1t: [N1][K] bf16; W2t: [N2][N1] bf16.
// 8 waves (512 thr), BM tokens/block. A-fragments kept in registers; H1 kept
// in LDS with T2 XOR swizzle (byte ^= (row&7)<<4); W-tiles staged per K-step
// (L2-resident, 1-deep prefetch).
// ---------------------------------------------------------------------------
template<int K, int N1, int N2, int BM, int EPI>
__global__ __launch_bounds__(512, 2) void fused_mlp_k(
    const bf16* __restrict__ A, const bf16* __restrict__ W1t, const float* __restrict__ b1,
    const bf16* __restrict__ W2t, const float* __restrict__ b2,
    void* __restrict__ Cout,
    const float* __restrict__ S, const float* __restrict__ lnw, const float* __restrict__ lnb)
{
  constexpr int WR  = BM / 32;          // wave rows (msg: 2, upd: 1)
  constexpr int WC  = 8 / WR;           // wave cols (msg: 4, upd: 8)
  constexpr int NIA = N1 / WC / 16;     // phase-A frags per wave (8 / 4)
  constexpr int NIB = N2 / WC / 16;     // phase-B frags per wave (4 / 2)
  constexpr int NSA = K  / 32;
  constexpr int NSB = N1 / 32;
  constexpr int H1SZ  = BM * N1 * 2;    // bytes
  constexpr int BSTSZ = N1 * 32 * 2;    // per staging buffer (>= N2*32*2)
  __shared__ alignas(16) char smem[H1SZ + 2*BSTSZ];

  const int t = threadIdx.x, lane = t & 63, wave = t >> 6;
  const int wr = wave / WC, wc = wave % WC;
  const int bm0 = blockIdx.x * BM;
  const int fRow = lane & 15, kq = lane >> 4, kOff = kq * 8;

  // ---- A fragments -> registers (no LDS staging for A) ----
  bf16x8 afr[2][NSA];
#pragma unroll
  for (int i = 0; i < 2; i++){
    const bf16* arow = A + (size_t)(bm0 + wr*32 + i*16 + fRow) * K + kOff;
#pragma unroll
    for (int kt = 0; kt < NSA; kt++)
      afr[i][kt] = *reinterpret_cast<const bf16x8*>(arow + kt*32);
  }

  auto stageB = [&](int buf, const bf16* W, int ldk, int nrows, int k0){
    bf16* dst = (bf16*)(smem + H1SZ + buf * BSTSZ);
    for (int u = t; u < nrows*4; u += 512)      // [nrows][32] tile; elem off = u*8
      async_ld16(W + (size_t)(u >> 2) * ldk + k0 + (u & 3) * 8, dst + u * 8);
  };

  f32x4 acc[2][NIA];
#pragma unroll
  for (int i = 0; i < 2; i++)
#pragma unroll
    for (int j = 0; j < NIA; j++)
#pragma unroll
      for (int r = 0; r < 4; r++) acc[i][j][r] = 0.f;

  // ---- phase A: H1 = gelu(A@W1 + b1) ----
  stageB(0, W1t, K, N1, 0);
  asm volatile("s_waitcnt vmcnt(0)" ::: "memory");
  __builtin_amdgcn_s_barrier();
  for (int kt = 0; kt < NSA; ++kt){
    const bf16* Bs = (const bf16*)(smem + H1SZ + (kt & 1) * BSTSZ);
    bf16x8 bf[NIA];
#pragma unroll
    for (int j = 0; j < NIA; j++)
      bf[j] = *reinterpret_cast<const bf16x8*>(&Bs[(wc*(N1/WC) + j*16 + fRow)*32 + kOff]);
    if (kt + 1 < NSA) stageB((kt + 1) & 1, W1t, K, N1, (kt + 1) * 32);
#pragma unroll
    for (int i = 0; i < 2; i++)
#pragma unroll
      for (int j = 0; j < NIA; j++)
        acc[i][j] = __builtin_amdgcn_mfma_f32_16x16x32_bf16(afr[i][kt], bf[j], acc[i][j], 0, 0, 0);
    asm volatile("s_waitcnt vmcnt(0)" ::: "memory");
    __builtin_amdgcn_s_barrier();
  }

  // gelu + swizzled H1 write (C/D layout: row=kq*4+r, col=fRow)
#pragma unroll
  for (int i = 0; i < 2; i++){
    const int row0 = wr*32 + i*16 + kq*4;
#pragma unroll
    for (int j = 0; j < NIA; j++){
      const int col = wc*(N1/WC) + j*16 + fRow;
      const float bv = b1[col];
#pragma unroll
      for (int r = 0; r < 4; r++){
        const int row = row0 + r;
        const float v = gelu_f(acc[i][j][r] + bv);
        const unsigned off = ((unsigned)(row*N1 + col)*2u) ^ ((unsigned)(row & 7) << 4);
        *(bf16*)(smem + off) = __float2bfloat16(v);
      }
    }
  }
  __syncthreads();

  // ---- phase B: C = H1 @ W2 + b2 ----
#pragma unroll
  for (int i = 0; i < 2; i++)
#pragma unroll
    for (int j = 0; j < NIB; j++)
#pragma unroll
      for (int r = 0; r < 4; r++) acc[i][j][r] = 0.f;

  stageB(0, W2t, N1, N2, 0);
  asm volatile("s_waitcnt vmcnt(0)" ::: "memory");
  __builtin_amdgcn_s_barrier();
  for (int kt = 0; kt < NSB; ++kt){
    bf16x8 af[2];
#pragma unroll
    for (int i = 0; i < 2; i++){
      const int row = wr*32 + i*16 + fRow;
      const unsigned off = ((unsigned)(row*N1 + kt*32 + kOff)*2u) ^ ((unsigned)(row & 7) << 4);
      af[i] = *(const bf16x8*)(smem + off);
    }
    const bf16* Bs = (const bf16*)(smem + H1SZ + (kt & 1) * BSTSZ);
    bf16x8 bf[NIB];
#pragma unroll
    for (int j = 0; j < NIB; j++)
      bf[j] = *reinterpret_cast<const bf16x8*>(&Bs[(wc*(N2/WC) + j*16 + fRow)*32 + kOff]);
    if (kt + 1 < NSB) stageB((kt + 1) & 1, W2t, N1, N2, (kt + 1) * 32);
#pragma unroll
    for (int i = 0; i < 2; i++)
#pragma unroll
      for (int j = 0; j < NIB; j++)
        acc[i][j] = __builtin_amdgcn_mfma_f32_16x16x32_bf16(af[i], bf[j], acc[i][j], 0, 0, 0);
    asm volatile("s_waitcnt vmcnt(0)" ::: "memory");
    __builtin_amdgcn_s_barrier();
  }

  if constexpr (EPI == 0){
    // bf16 C store via LDS for coalesced b128 writes
    __syncthreads();
    constexpr int CTS = N2 + 8;
    bf16* Ct = (bf16*)smem;
#pragma unroll
    for (int i = 0; i < 2; i++){
      const int row0 = wr*32 + i*16 + kq*4;
#pragma unroll
      for (int j = 0; j < NIB; j++){
        const int col = wc*(N2/WC) + j*16 + fRow;
        const float bv = b2[col];
#pragma unroll
        for (int r = 0; r < 4; r++)
          Ct[(row0 + r)*CTS + col] = __float2bfloat16(acc[i][j][r] + bv);
      }
    }
    __syncthreads();
    for (int u = t; u < BM*N2/8; u += 512){
      const int row = u / (N2/8), c8 = (u % (N2/8)) * 8;
      ushort8s v = *reinterpret_cast<const ushort8s*>(&Ct[row*CTS + c8]);
      *reinterpret_cast<ushort8s*>((bf16*)Cout + (size_t)(bm0 + row)*N2 + c8) = v;
    }
  } else {
    // fused residual + LayerNorm: rows are complete (N2 == D == full row width)
    float vals[2][NIB][4];
#pragma unroll
    for (int i = 0; i < 2; i++){
      const int row0 = i*16 + kq*4;         // wr == 0 when EPI==1 (WR=1)
#pragma unroll
      for (int j = 0; j < NIB; j++){
        const int col = wc*(N2/WC) + j*16 + fRow;
        const float bv = b2[col];
#pragma unroll
        for (int r = 0; r < 4; r++)
          vals[i][j][r] = S[(size_t)(bm0 + row0 + r)*N2 + col] + acc[i][j][r] + bv;
      }
    }
    __syncthreads();                        // smem free for reduction
    float* red = (float*)smem;              // [32 rows][8 waves][2]
#pragma unroll
    for (int i = 0; i < 2; i++)
#pragma unroll
      for (int r = 0; r < 4; r++){
        float s = 0.f, q = 0.f;
#pragma unroll
        for (int j = 0; j < NIB; j++){ s += vals[i][j][r]; q += vals[i][j][r]*vals[i][j][r]; }
        s += __shfl_xor(s, 1); s += __shfl_xor(s, 2); s += __shfl_xor(s, 4); s += __shfl_xor(s, 8);
        q += __shfl_xor(q, 1); q += __shfl_xor(q, 2); q += __shfl_xor(q, 4); q += __shfl_xor(q, 8);
        if (fRow == 0){
          const int row = i*16 + kq*4 + r;
          red[(row*8 + wave)*2 + 0] = s;
          red[(row*8 + wave)*2 + 1] = q;
        }
      }
    __syncthreads();
    float* mur = (float*)smem + 512;
    if (t < 32){
      float s = 0.f, q = 0.f;
      for (int w2 = 0; w2 < 8; w2++){ s += red[(t*8 + w2)*2]; q += red[(t*8 + w2)*2 + 1]; }
      const float mu = s * (1.f/256.f);
      const float var = q * (1.f/256.f) - mu*mu;
      mur[t*2] = mu; mur[t*2 + 1] = rsqrtf(var + 1e-5f);
    }
    __syncthreads();
#pragma unroll
    for (int i = 0; i < 2; i++){
      const int row0 = i*16 + kq*4;
#pragma unroll
      for (int j = 0; j < NIB; j++){
        const int col = wc*(N2/WC) + j*16 + fRow;
        const float lw = lnw[col], lb = lnb[col];
#pragma unroll
        for (int r = 0; r < 4; r++){
          const int row = row0 + r;
          ((float*)Cout)[(size_t)(bm0 + row)*N2 + col] =
              (vals[i][j][r] - mur[row*2]) * mur[row*2 + 1] * lw + lb;
        }
      }
    }
  }
}

// gelu(X@Wg1+bg1) GEMM with gate-dot epilogue (unchanged from R4)
__global__ __launch_bounds__(256) void gate_gemm_k(const bf16* __restrict__ A, const bf16* __restrict__ Wt,
                                                   const float* __restrict__ bias, const float* __restrict__ Wg2,
                                                   float* __restrict__ gacc)
{
  constexpr int N = 256, K = 256, BM = 128, BN = 128, BK = 32;
  constexpr int NSTEP = K / BK, TILEB = (BM + BN) * BK;
  __shared__ alignas(16) bf16 bufs[3 * TILEB];

  constexpr int nblk = N / BN;
  const int bm = (int)(blockIdx.x / nblk) * BM;
  const int bn = (int)(blockIdx.x % nblk) * BN;
  const int t = threadIdx.x, lane = t & 63, wave = t >> 6;
  const int wm = (wave >> 1) * 64, wn = (wave & 1) * 64;
  const int fRow = lane & 15, kOff = (lane >> 4) * 8;

  f32x4 acc[4][4] = {};

  auto stage = [&](int buf, int k0){
    bf16* As = bufs + buf * TILEB;
    bf16* Bs = As + BM * BK;
#pragma unroll
    for (int i = t; i < BM * 4; i += 256)
      async_ld16(A + (size_t)(bm + (i >> 2)) * K + k0 + (i & 3) * 8, As + i * 8);
#pragma unroll
    for (int i = t; i < BN * 4; i += 256)
      async_ld16(Wt + (size_t)(bn + (i >> 2)) * K + k0 + (i & 3) * 8, Bs + i * 8);
  };

  stage(0, 0);
  stage(1, BK);
  asm volatile("s_waitcnt vmcnt(4)" ::: "memory");

  for (int kt = 0; kt < NSTEP; ++kt){
    __builtin_amdgcn_s_barrier();
    asm volatile("" ::: "memory");
    const bf16* As = bufs + (kt % 3) * TILEB;
    const bf16* Bs = As + BM * BK;
    bf16x8 af[4], bfv[4];
#pragma unroll
    for (int i = 0; i < 4; i++)
      af[i]  = *reinterpret_cast<const bf16x8*>(&As[(wm + i*16 + fRow)*BK + kOff]);
#pragma unroll
    for (int j = 0; j < 4; j++)
      bfv[j] = *reinterpret_cast<const bf16x8*>(&Bs[(wn + j*16 + fRow)*BK + kOff]);
    if (kt + 2 < NSTEP) stage((kt + 2) % 3, (kt + 2) * BK);
#pragma unroll
    for (int i = 0; i < 4; i++)
#pragma unroll
      for (int j = 0; j < 4; j++)
        acc[i][j] = __builtin_amdgcn_mfma_f32_16x16x32_bf16(af[i], bfv[j], acc[i][j], 0, 0, 0);
    if (kt + 2 < NSTEP) asm volatile("s_waitcnt vmcnt(4)" ::: "memory");
    else asm volatile("s_waitcnt vmcnt(0)" ::: "memory");
  }

  const int c16 = lane & 15, q = lane >> 4;
  float wv[4], bvv[4];
#pragma unroll
  for (int j = 0; j < 4; j++){
    const int col = bn + wn + j*16 + c16;
    wv[j] = Wg2[col];
    bvv[j] = bias[col];
  }
#pragma unroll
  for (int i = 0; i < 4; i++){
#pragma unroll
    for (int r = 0; r < 4; r++){
      float p = 0.f;
#pragma unroll
      for (int j = 0; j < 4; j++) p += gelu_f(acc[i][j][r] + bvv[j]) * wv[j];
      p += __shfl_xor(p, 1); p += __shfl_xor(p, 2); p += __shfl_xor(p, 4); p += __shfl_xor(p, 8);
      if (c16 == 0) atomicAdd(&gacc[bm + wm + i*16 + q*4 + r], p);
    }
  }
}

// fp32 routing GEMM (unchanged from R4)
__global__ __launch_bounds__(256) void route4_k(const float* __restrict__ X,
                                                const float* __restrict__ Wcat,
                                                int* __restrict__ slot_out)
{
  __shared__ float lds[128 * 84];
  float* Xs = lds;                      // [16][136]
  float* Ws = lds + 16 * 136;           // [16][80]
  float* Cs = lds;                      // [128][84] epilogue alias

  const int t = threadIdx.x;
  const int tok0 = blockIdx.x * 128;
  const int cq = t & 15;
  const int tg = t >> 4;
  const int stok = t >> 2, skq = t & 3;

  const float* xsrc0 = X + (size_t)(tok0 + stok) * D + 4*skq;
  const float* xsrc1 = X + (size_t)(tok0 + 64 + stok) * D + 4*skq;
  const int wrow0 = t / 20,        wc0 = t - wrow0*20;
  const int wrow1 = (256+t) / 20,  wc1 = (256+t) - wrow1*20;

  float accg[8][4] = {};
  float accs[8] = {};

  float4 xr0 = *reinterpret_cast<const float4*>(xsrc0);
  float4 xr1 = *reinterpret_cast<const float4*>(xsrc1);
  float4 wr0 = *reinterpret_cast<const float4*>(Wcat + (size_t)wrow0*80 + 4*wc0);
  float4 wr1;
  if (t < 64) wr1 = *reinterpret_cast<const float4*>(Wcat + (size_t)wrow1*80 + 4*wc1);

  for (int kt = 0; kt < 16; ++kt){
    __syncthreads();
    Xs[(4*skq+0)*136 + stok] = xr0.x;
    Xs[(4*skq+1)*136 + stok] = xr0.y;
    Xs[(4*skq+2)*136 + stok] = xr0.z;
    Xs[(4*skq+3)*136 + stok] = xr0.w;
    Xs[(4*skq+0)*136 + 64 + stok] = xr1.x;
    Xs[(4*skq+1)*136 + 64 + stok] = xr1.y;
    Xs[(4*skq+2)*136 + 64 + stok] = xr1.z;
    Xs[(4*skq+3)*136 + 64 + stok] = xr1.w;
    *reinterpret_cast<float4*>(&Ws[wrow0*80 + 4*wc0]) = wr0;
    if (t < 64) *reinterpret_cast<float4*>(&Ws[wrow1*80 + 4*wc1]) = wr1;
    __syncthreads();
    if (kt < 15){
      const int ko = (kt+1)*16;
      xr0 = *reinterpret_cast<const float4*>(xsrc0 + ko);
      xr1 = *reinterpret_cast<const float4*>(xsrc1 + ko);
      wr0 = *reinterpret_cast<const float4*>(Wcat + (size_t)(ko + wrow0)*80 + 4*wc0);
      if (t < 64) wr1 = *reinterpret_cast<const float4*>(Wcat + (size_t)(ko + wrow1)*80 + 4*wc1);
    }
#pragma unroll
    for (int k = 0; k < 16; ++k){
      const float4 xa = *reinterpret_cast<const float4*>(&Xs[k*136 + tg*8]);
      const float4 xb = *reinterpret_cast<const float4*>(&Xs[k*136 + tg*8 + 4]);
      const float4 wq = *reinterpret_cast<const float4*>(&Ws[k*80 + 4*cq]);
      const float wsv = Ws[k*80 + 64 + cq];
      const float xv[8] = {xa.x, xa.y, xa.z, xa.w, xb.x, xb.y, xb.z, xb.w};
#pragma unroll
      for (int m = 0; m < 8; m++){
        accg[m][0] = fmaf(xv[m], wq.x, accg[m][0]);
        accg[m][1] = fmaf(xv[m], wq.y, accg[m][1]);
        accg[m][2] = fmaf(xv[m], wq.z, accg[m][2]);
        accg[m][3] = fmaf(xv[m], wq.w, accg[m][3]);
        accs[m]    = fmaf(xv[m], wsv,  accs[m]);
      }
    }
  }

  __syncthreads();
#pragma unroll
  for (int m = 0; m < 8; m++){
    const int tok = tg*8 + m;
    Cs[tok*84 + 4*cq + 0] = accg[m][0];
    Cs[tok*84 + 4*cq + 1] = accg[m][1];
    Cs[tok*84 + 4*cq + 2] = accg[m][2];
    Cs[tok*84 + 4*cq + 3] = accg[m][3];
    Cs[tok*84 + 64 + cq]  = accs[m];
  }
  __syncthreads();
  if (t < 128){
    const float* row = &Cs[t * 84];
    float bg = row[0]; int big = 0;
    for (int g = 1; g < 64; ++g){ const float v = row[g]; if (v > bg){ bg = v; big = g; } }
    float bs = row[64]; int bis = 0;
    for (int s2 = 1; s2 < 16; ++s2){ const float v = row[64 + s2]; if (v > bs){ bs = v; bis = s2; } }
    slot_out[tok0 + t] = big * KK + bis;
  }
}

__global__ void scatter_k(const bf16* __restrict__ MSG, const float* __restrict__ gacc,
                          const float* __restrict__ bg2, const int* __restrict__ slot,
                          float* __restrict__ inc)
{
  const int d  = threadIdx.x;
  const int t0 = blockIdx.x * 16;
  const float bg2v = bg2[0];
  for (int i = 0; i < 16; i++){
    const int tok = t0 + i;
    const float g = 1.f / (1.f + __expf(-(gacc[tok] + bg2v)));
    const int s = slot[tok];
    const int b = tok >> 12;   // tok / L, L=4096
    const float v = __bfloat162float(MSG[(size_t)tok*D + d]) * g;
    atomicAdd(&inc[((size_t)(b*NN + s))*D + d], v);
  }
}

__global__ void concat_k(const float* __restrict__ S, const float* __restrict__ inc,
                         bf16* __restrict__ Hb)
{
  const int i8 = blockIdx.x*256 + threadIdx.x;   // over NSLOT*TWOD/8
  const int r = i8 >> 6, c = (i8 & 63) * 8;
  const float* src = (c < D) ? (S + (size_t)r*D + c) : (inc + (size_t)r*D + (c - D));
  const float4 a = reinterpret_cast<const float4*>(src)[0];
  const float4 b = reinterpret_cast<const float4*>(src)[1];
  ushort8s o;
  o.v[0] = __bfloat16_as_ushort(__float2bfloat16(a.x));
  o.v[1] = __bfloat16_as_ushort(__float2bfloat16(a.y));
  o.v[2] = __bfloat16_as_ushort(__float2bfloat16(a.z));
  o.v[3] = __bfloat16_as_ushort(__float2bfloat16(a.w));
  o.v[4] = __bfloat16_as_ushort(__float2bfloat16(b.x));
  o.v[5] = __bfloat16_as_ushort(__float2bfloat16(b.y));
  o.v[6] = __bfloat16_as_ushort(__float2bfloat16(b.z));
  o.v[7] = __bfloat16_as_ushort(__float2bfloat16(b.w));
  reinterpret_cast<ushort8s*>(Hb)[i8] = o;
}

} // namespace

extern "C" void kernel_launch(void* const* d_in, const int* in_sizes, int n_in,
                              void* d_out, int out_size, void* d_ws, size_t ws_size,
                              hipStream_t stream)
{
  (void)in_sizes; (void)n_in; (void)out_size; (void)ws_size;
  const float* X   = (const float*)d_in[0];
  const float* S   = (const float*)d_in[1];
  const float* Wgr = (const float*)d_in[2];
  const float* Wsl = (const float*)d_in[3];
  const float* Wm1 = (const float*)d_in[4];
  const float* bm1 = (const float*)d_in[5];
  const float* Wm2 = (const float*)d_in[6];
  const float* bm2 = (const float*)d_in[7];
  const float* Wg1 = (const float*)d_in[8];
  const float* bg1 = (const float*)d_in[9];
  const float* Wg2 = (const float*)d_in[10];
  const float* bg2 = (const float*)d_in[11];
  const float* Wu1 = (const float*)d_in[12];
  const float* bu1 = (const float*)d_in[13];
  const float* Wu2 = (const float*)d_in[14];
  const float* bu2 = (const float*)d_in[15];
  const float* lnw = (const float*)d_in[16];
  const float* lnb = (const float*)d_in[17];
  float* out = (float*)d_out;

  char* ws = (char*)d_ws;
  bf16* Xb   = (bf16*)(ws + 0);            // 16,777,216 B
  bf16* MSG  = (bf16*)(ws + 50331648);     // 16,777,216 B
  bf16* Wm1t = (bf16*)(ws + 67108864);     // 512x256
  bf16* Wm2t = (bf16*)(ws + 67108864 + 262144);   // 256x512
  bf16* Wg1t = (bf16*)(ws + 67108864 + 524288);   // 256x256
  bf16* Wu1t = (bf16*)(ws + 67108864 + 655360);   // 512x512
  bf16* Wu2t = (bf16*)(ws + 67108864 + 1179648);  // 256x512
  int*   slot = (int*)  (ws + 68550656);
  float* gacc = (float*)(ws + 68681728);   // 131072 B
  float* inc  = (float*)(ws + 68812800);   // 8,388,608 B
  bf16*  Hb   = (bf16*)(ws + 0);           // alias Xb (dead after gate_gemm/fused_msg)
  float* Wcat = (float*)(ws + 68812800);   // alias inc: dead before memset(inc)

  cvt_f32_to_bf16_k<<<4096, 256, 0, stream>>>((const float4*)X, (bf16x4s*)Xb, NTOK*D/4);
  transpose_w_k<<<(256*512+255)/256, 256, 0, stream>>>(Wm1, Wm1t, 256, 512);
  transpose_w_k<<<(512*256+255)/256, 256, 0, stream>>>(Wm2, Wm2t, 512, 256);
  transpose_w_k<<<(256*256+255)/256, 256, 0, stream>>>(Wg1, Wg1t, 256, 256);
  transpose_w_k<<<(512*512+255)/256, 256, 0, stream>>>(Wu1, Wu1t, 512, 512);
  transpose_w_k<<<(512*256+255)/256, 256, 0, stream>>>(Wu2, Wu2t, 512, 256);
  cat_w_k<<<(256*80+255)/256, 256, 0, stream>>>(Wgr, Wsl, Wcat);

  // fused msg MLP: MSG = gelu(Xb@Wm1+bm1)@Wm2 + bm2
  fused_mlp_k<256, 512, 256, 64, 0><<<NTOK/64, 512, 0, stream>>>(
      Xb, Wm1t, bm1, Wm2t, bm2, MSG, nullptr, nullptr, nullptr);

  hipMemsetAsync(gacc, 0, (size_t)NTOK*sizeof(float), stream);
  gate_gemm_k<<<(NTOK/128)*2, 256, 0, stream>>>(Xb, Wg1t, bg1, Wg2, gacc);

  route4_k<<<NTOK/128, 256, 0, stream>>>(X, Wcat, slot);

  hipMemsetAsync(inc, 0, (size_t)NSLOT*D*sizeof(float), stream);
  scatter_k<<<NTOK/16, 256, 0, stream>>>(MSG, gacc, bg2, slot, inc);
  concat_k<<<NSLOT*TWOD/8/256, 256, 0, stream>>>(S, inc, Hb);

  // fused slot-update MLP + residual + LayerNorm -> out
  fused_mlp_k<512, 512, 256, 32, 1><<<NSLOT/32, 512, 0, stream>>>(
      Hb, Wu1t, bu1, Wu2t, bu2, out, S, lnw, lnb);
}